// Round 15
// baseline (76.770 us; speedup 1.0000x reference)
//
#include <hip/hip_runtime.h>
#include <cstdint>
#include <cstddef>

// ---------------------------------------------------------------------------
// Attention_Param_sharing_Kv_sharing: B=4, C=256, H=W=64 (N=4096), KD=16,
// NH=8, DH=128.  Gram-matrix attention, one shared KV head.
//
// R14 (verified, 69.9us total / 53.6 attn): swapped 32x32x16 flash + fused
//   output projection; 8 waves/block = 2 waves/SIMD -> serial chain exposed.
// R15: 16 waves/block (1024 thr) via 8 key-streams x 512 keys, 32-key V
//   tiles (8 KB): LDS 8x2x8=128 KB, grid still (64,4)=256 blocks=1/CU,
//   4 waves/SIMD.  Tile body = first half of verified R13 body (1 S-MFMA +
//   2 PV chunks).  8-way merge (Opart spans all v_lds; olds overlaps ->
//   read-to-reg, barrier, write).  Epilogue: 16 waves x 16-o tiles.
// ---------------------------------------------------------------------------

typedef __attribute__((ext_vector_type(4)))  float f32x4;
typedef __attribute__((ext_vector_type(16))) float f32x16;
typedef __attribute__((ext_vector_type(8)))  _Float16 half8;
typedef __attribute__((ext_vector_type(8)))  unsigned short ushort8;
typedef __attribute__((ext_vector_type(2)))  unsigned u32x2;
typedef __attribute__((ext_vector_type(4)))  unsigned u32x4;

#define N_SP 4096
#define CIN  256
#define KDIM 16
#define DHV  128

__device__ __forceinline__ unsigned short f2h(float f) {
    _Float16 h = (_Float16)f;             // RNE
    return __builtin_bit_cast(unsigned short, h);
}
__device__ __forceinline__ float h2f(unsigned short u) {
    return (float)__builtin_bit_cast(_Float16, u);
}
__device__ __forceinline__ unsigned pk2(float a, float b) {
    return (unsigned)f2h(a) | ((unsigned)f2h(b) << 16);
}
__device__ __forceinline__ unsigned shfl32u(unsigned v, int src) {
    return (unsigned)__shfl((int)v, src, 64);
}
__device__ __forceinline__ f32x4 mfma16(ushort8 a, ushort8 b, f32x4 c) {
    return __builtin_amdgcn_mfma_f32_16x16x32_f16(
        __builtin_bit_cast(half8, a), __builtin_bit_cast(half8, b), c, 0, 0, 0);
}
__device__ __forceinline__ f32x16 mfma32(half8 a, half8 b, f32x16 c) {
    return __builtin_amdgcn_mfma_f32_32x32x16_f16(a, b, c, 0, 0, 0);
}

// ---------------------------------------------------------------------------
// Kernel 0: fold BN into weights.  qk rows pre-scaled by sqrt(log2 e) so
// S arrives multiplied by log2(e) (exp2-domain softmax downstream).
// ---------------------------------------------------------------------------
__global__ __launch_bounds__(256) void fold_weights(
    const float* __restrict__ w_qk, const float* __restrict__ g_qk,
    const float* __restrict__ b_qk, const float* __restrict__ m_qk,
    const float* __restrict__ v_qk,
    const float* __restrict__ w_v, const float* __restrict__ g_v,
    const float* __restrict__ b_v, const float* __restrict__ m_v,
    const float* __restrict__ v_v,
    const float* __restrict__ w_p, const float* __restrict__ g_p,
    const float* __restrict__ b_p, const float* __restrict__ m_p,
    const float* __restrict__ v_p,
    unsigned short* __restrict__ wf1, float* __restrict__ shift1,
    unsigned short* __restrict__ wpf, float* __restrict__ shiftp)
{
    const float SQL2E = 1.2011224087864498f;   // sqrt(log2 e)
    int row = blockIdx.x;
    int t   = threadIdx.x;
    if (row < 144) {
        float s, sh; const float* src;
        if (row < KDIM) {
            s  = g_qk[row] * rsqrtf(v_qk[row] + 1e-5f);
            sh = b_qk[row] - m_qk[row] * s;
            s *= SQL2E; sh *= SQL2E;           // exp2-domain pre-scale
            src = w_qk + row * CIN;
        } else {
            int o = row - KDIM;
            s  = g_v[o] * rsqrtf(v_v[o] + 1e-5f);
            sh = b_v[o] - m_v[o] * s;
            src = w_v + o * CIN;
        }
        wf1[row * CIN + t] = f2h(src[t] * s);
        if (t == 0) shift1[row] = sh;
    } else {
        int o = row - 144;
        float s = g_p[o] * rsqrtf(v_p[o] + 1e-5f);
        if (t < DHV) wpf[o * DHV + t] = f2h(w_p[o * DHV + t] * s);
        if (t == 0) shiftp[o] = b_p[o] - m_p[o] * s;
    }
}

// ---------------------------------------------------------------------------
// Kernel 1: projection GEMM (x read once), unchanged from R14 (verified).
// ---------------------------------------------------------------------------
__global__ __launch_bounds__(512) void proj_qkv(
    const float* __restrict__ x,
    const unsigned short* __restrict__ wf1, const float* __restrict__ shift1,
    unsigned short* __restrict__ qkT, unsigned short* __restrict__ Vt)
{
    const int b  = blockIdx.y;
    const int n0 = blockIdx.x * 64;
    const int tid  = threadIdx.x;
    const int w    = tid >> 6;
    const int half = w >> 2;
    const int wq   = w & 3;
    const int lane = tid & 63;
    const int lg   = lane >> 4;
    const int lr   = lane & 15;
    const int n    = n0 + wq * 16 + lr;

    const float* xb = x + (size_t)b * CIN * N_SP;

    if (half == 0) {
        f32x4 acc[5];
#pragma unroll
        for (int i = 0; i < 5; ++i) acc[i] = (f32x4){0.f, 0.f, 0.f, 0.f};
        for (int ks = 0; ks < 8; ++ks) {
            const int cbase = ks * 32 + lg * 8;
            ushort8 bx;
#pragma unroll
            for (int j = 0; j < 8; ++j)
                bx[j] = f2h(xb[(size_t)(cbase + j) * N_SP + n]);
#pragma unroll
            for (int i = 0; i < 5; ++i) {
                ushort8 a = *(const ushort8*)(wf1 + (i * 16 + lr) * CIN + cbase);
                acc[i] = mfma16(a, bx, acc[i]);
            }
        }
#pragma unroll
        for (int i = 0; i < 5; ++i)
#pragma unroll
            for (int r = 0; r < 4; ++r) {
                int o = i * 16 + lg * 4 + r;
                float val = acc[i][r] + shift1[o];
                unsigned short hv = f2h(val);
                if (o < KDIM) qkT[((size_t)b * N_SP + n) * 16 + o] = hv;
                else          Vt[((size_t)b * DHV + (o - KDIM)) * N_SP + n] = hv;
            }
    } else {
        f32x4 acc[4];
#pragma unroll
        for (int i = 0; i < 4; ++i) acc[i] = (f32x4){0.f, 0.f, 0.f, 0.f};
        for (int ks = 0; ks < 8; ++ks) {
            const int cbase = ks * 32 + lg * 8;
            ushort8 bx;
#pragma unroll
            for (int j = 0; j < 8; ++j)
                bx[j] = f2h(xb[(size_t)(cbase + j) * N_SP + n]);
#pragma unroll
            for (int i = 0; i < 4; ++i) {
                ushort8 a = *(const ushort8*)(wf1 + ((i + 5) * 16 + lr) * CIN + cbase);
                acc[i] = mfma16(a, bx, acc[i]);
            }
        }
#pragma unroll
        for (int i = 0; i < 4; ++i)
#pragma unroll
            for (int r = 0; r < 4; ++r) {
                int o = (i + 5) * 16 + lg * 4 + r;
                float val = acc[i][r] + shift1[o];
                Vt[((size_t)b * DHV + (o - KDIM)) * N_SP + n] = f2h(val);
            }
    }
}

// ---------------------------------------------------------------------------
// Stage one 32-key V tile (128 d x 32 halves = 8 KB) via global_load_lds,
// 8 x 1KB chunks; wave p of the stream issues chunks [p*4, p*4+4).
// Row = 64 B = 4 slots of 16 B.  Source pre-swizzled (rule 21): physical
// slot s of row d holds logical slot s ^ (d&3).
// ---------------------------------------------------------------------------
__device__ __forceinline__ void stage_v(
    const unsigned short* __restrict__ vt_b,
    unsigned short* v_l, int k0, int p, int lane)
{
#pragma unroll
    for (int s = 0; s < 4; ++s) {
        const int vi   = p * 4 + s;
        const int dloc = lane >> 2;
        const int d    = vi * 16 + dloc;
        const int c4   = (lane & 3) ^ (dloc & 3);
        const unsigned short* src = vt_b + (size_t)d * N_SP + k0 + c4 * 8;
        __builtin_amdgcn_global_load_lds(
            (const __attribute__((address_space(1))) void*)src,
            (__attribute__((address_space(3))) void*)(v_l + vi * 512),
            16, 0, 0);
    }
}

// V A-frag for PV: A[m=d][k]: lane&31 = d-row, k = (lane>>5)*8 + j.
// Row stride 32 ushorts (64 B); logical slot = kc*2+hi, phys = ^(d&3).
__device__ __forceinline__ half8 ldv(const unsigned short* vl, int nb, int kc,
                                     int la31, int hi)
{
    const int d = nb * 32 + la31;
    const ushort8 v = *(const ushort8*)
        (vl + d * 32 + (((kc * 2 + hi) ^ (d & 3)) << 3));
    return __builtin_bit_cast(half8, v);
}

// K A-frag for S: A[m=key][k]: lane&31 = key-row, k = (lane>>5)*8 + j.
__device__ __forceinline__ half8 ldk(const unsigned short* qk_b, int krow,
                                     int la31, int hi)
{
    return __builtin_bit_cast(half8,
        *(const ushort8*)(qk_b + (size_t)(krow + la31) * 16 + hi * 8));
}

// ---------------------------------------------------------------------------
// Kernel 2: flash attention + fused output projection, 16 waves.
// Grid (64, B), 1024 thr = 16 waves = 8 streams x 2 q-waves.  Stream s:
// keys [s*512,(s+1)*512) in 16 tiles of 32; wave p: queries q0+p*32..+31.
// ---------------------------------------------------------------------------
__global__ __launch_bounds__(1024, 4) void attn_kernel(
    const unsigned short* __restrict__ qkT,   // [b][n][16] f16 (x sqrt(log2e))
    const unsigned short* __restrict__ Vt,    // [b][128][n] f16
    const unsigned short* __restrict__ wpf,   // [256][128] f16
    const float* __restrict__ shiftp,         // [256] f32
    float* __restrict__ out)                  // [b][256][4096] f32
{
    const int b  = blockIdx.y;
    const int q0 = blockIdx.x * 64;
    const int tid  = threadIdx.x;
    const int ws   = tid >> 6;         // wave 0..15
    const int strm = ws >> 1;          // key-stream 0..7
    const int p    = ws & 1;           // q-half 0..1
    const int lane = tid & 63;
    const int la31 = lane & 31;
    const int hi   = lane >> 5;

    const unsigned short* qk_b = qkT + (size_t)b * N_SP * 16;
    const unsigned short* vt_b = Vt  + (size_t)b * DHV * N_SP;
    const int kbase = strm * (N_SP / 8);   // 512 keys per stream
    const int qrow  = q0 + p * 32;

    // Q B-frag (col n = query = lane&31, k = hi*8+j)
    const half8 aq = __builtin_bit_cast(half8,
        *(const ushort8*)(qk_b + (size_t)(qrow + la31) * 16 + hi * 8));

    f32x16 acc0, acc1, acc2, acc3, z16;
#pragma unroll
    for (int i = 0; i < 16; ++i) { z16[i] = 0.f; }
    acc0 = z16; acc1 = z16; acc2 = z16; acc3 = z16;
    float m_r = -__builtin_inff();
    float l_r = 0.f;

    __shared__ __align__(16) unsigned short v_lds[8][2][128 * 32];  // 128 KB
    __shared__ float lmbuf[8][64][2];                               // 4 KB

    stage_v(vt_b, &v_lds[strm][0][0], kbase, p, lane);
    half8 kf0n = ldk(qk_b, kbase, la31, hi);   // K prefetch, tile 0

    for (int t = 0; t < 16; ++t) {
        const int cur = t & 1;
        __syncthreads();            // buf[cur] + kf0n ready; prior reads done
        if (t < 15)
            stage_v(vt_b, &v_lds[strm][cur ^ 1][0], kbase + (t + 1) * 32,
                    p, lane);
        const half8 kf0 = kf0n;
        if (t < 15)                 // prefetch K for tile t+1
            kf0n = ldk(qk_b, kbase + (t + 1) * 32, la31, hi);
        const unsigned short* vl = &v_lds[strm][cur][0];

        // ---- S' = (K Q^T) * log2e --------------------------------------
        f32x16 s0 = mfma32(kf0, aq, z16);     // 32 keys

        // ---- in-lane softmax, 2-domain ----------------------------------
        float mpair[8];
#pragma unroll
        for (int i = 0; i < 8; ++i) mpair[i] = fmaxf(s0[i], s0[i + 8]);
        float mx = fmaxf(fmaxf(fmaxf(mpair[0], mpair[1]), fmaxf(mpair[2], mpair[3])),
                         fmaxf(fmaxf(mpair[4], mpair[5]), fmaxf(mpair[6], mpair[7])));
        mx = fmaxf(mx, __shfl(mx, lane ^ 32));   // other 16 keys on lane^32

        // defer-max: THR = 8*log2e = 11.54 (P <= e^8, fp16-safe)
        if (!__all(mx <= m_r + 11.54f)) {
            float mnew = fmaxf(m_r, mx);
            float sc = exp2f(m_r - mnew);         // first tile: exp2(-inf)=0
            l_r *= sc;
#pragma unroll
            for (int i = 0; i < 16; ++i) {
                acc0[i] *= sc; acc1[i] *= sc; acc2[i] *= sc; acc3[i] *= sc;
            }
            m_r = mnew;
        }
#pragma unroll
        for (int i = 0; i < 16; ++i) s0[i] = exp2f(s0[i] - m_r);
        float rpair[8];
#pragma unroll
        for (int i = 0; i < 8; ++i) rpair[i] = s0[i] + s0[i + 8];
        l_r += ((rpair[0] + rpair[1]) + (rpair[2] + rpair[3]))
             + ((rpair[4] + rpair[5]) + (rpair[6] + rpair[7]));

        // ---- O += V^T P (2 chunks of 16 keys) ----------------------------
#define PV_CHUNK(SV, B0, KC)                                               \
        {                                                                  \
            unsigned a0 = pk2(SV[B0 + 0], SV[B0 + 1]);                     \
            unsigned a1 = pk2(SV[B0 + 2], SV[B0 + 3]);                     \
            unsigned a2 = pk2(SV[B0 + 4], SV[B0 + 5]);                     \
            unsigned a3 = pk2(SV[B0 + 6], SV[B0 + 7]);                     \
            unsigned p0 = shfl32u(a0, lane ^ 32);                          \
            unsigned p1 = shfl32u(a1, lane ^ 32);                          \
            unsigned p2 = shfl32u(a2, lane ^ 32);                          \
            unsigned p3 = shfl32u(a3, lane ^ 32);                          \
            u32x4 pw;                                                      \
            pw.x = hi ? p2 : a0;                                           \
            pw.y = hi ? p3 : a1;                                           \
            pw.z = hi ? a2 : p0;                                           \
            pw.w = hi ? a3 : p1;                                           \
            half8 pb = __builtin_bit_cast(half8, pw);                      \
            acc0 = mfma32(ldv(vl, 0, KC, la31, hi), pb, acc0);             \
            acc1 = mfma32(ldv(vl, 1, KC, la31, hi), pb, acc1);             \
            acc2 = mfma32(ldv(vl, 2, KC, la31, hi), pb, acc2);             \
            acc3 = mfma32(ldv(vl, 3, KC, la31, hi), pb, acc3);             \
        }
        PV_CHUNK(s0, 0, 0)
        PV_CHUNK(s0, 8, 1)
#undef PV_CHUNK
    }

    // ---- finish l: other 16 keys live on lane^32 --------------------------
    l_r = l_r + __shfl(l_r, lane ^ 32);

    __syncthreads();   // all streams done reading V bufs -> safe to reuse

    // ---- publish normalized partial O (fp16) + (m,l) ----------------------
    unsigned short* Opart = &v_lds[0][0][0];  // [8 streams][64 q][128 d] f16
    const int qib = p * 32 + la31;
    if (hi == 0) {
        lmbuf[strm][qib][0] = m_r;
        lmbuf[strm][qib][1] = l_r;
    }
    {
        const float invl = 1.0f / l_r;
        const size_t qoff = ((size_t)strm * 64 + qib) * 128;
#define PUB(ACC, NB)                                                       \
        {                                                                  \
            _Pragma("unroll")                                              \
            for (int rq = 0; rq < 4; ++rq) {                               \
                float v0 = ACC[rq * 4 + 0] * invl;                         \
                float v1 = ACC[rq * 4 + 1] * invl;                         \
                float v2 = ACC[rq * 4 + 2] * invl;                         \
                float v3 = ACC[rq * 4 + 3] * invl;                         \
                u32x2 wv; wv.x = pk2(v0, v1); wv.y = pk2(v2, v3);          \
                *(u32x2*)(Opart + qoff + NB * 32 + rq * 8 + 4 * hi) = wv;  \
            }                                                              \
        }
        PUB(acc0, 0) PUB(acc1, 1) PUB(acc2, 2) PUB(acc3, 3)
#undef PUB
    }
    __syncthreads();

    // ---- merge 8 streams (read all to regs, barrier, write olds) ----------
    // thread t: q = t>>4 (0..63), dseg = (t&15)*8 (8 halves = 16 B)
    unsigned short* olds = &v_lds[0][0][0];   // [64][136] f16, overlaps Opart
    {
        const int q    = tid >> 4;
        const int dseg = (tid & 15) * 8;

        ushort8 part[8];
        float   wgt[8];
        float M = -__builtin_inff();
#pragma unroll
        for (int s = 0; s < 8; ++s) M = fmaxf(M, lmbuf[s][q][0]);
        float wsum = 0.f;
#pragma unroll
        for (int s = 0; s < 8; ++s) {
            wgt[s] = lmbuf[s][q][1] * exp2f(lmbuf[s][q][0] - M);
            wsum += wgt[s];
            part[s] = *(const ushort8*)(Opart + ((size_t)s * 64 + q) * 128 + dseg);
        }
        const float inv = 1.0f / wsum;

        ushort8 o8;
#pragma unroll
        for (int i = 0; i < 8; ++i) {
            float v = 0.f;
#pragma unroll
            for (int s = 0; s < 8; ++s) v += wgt[s] * h2f(part[s][i]);
            o8[i] = f2h(fmaxf(v * inv, 0.f));   // normalize + relu
        }
        __syncthreads();   // all Opart reads done before olds overwrite
        *(ushort8*)(olds + q * 136 + dseg) = o8;
    }
    __syncthreads();

    // ---- fused output projection: out[b][256][q0..q0+64) ------------------
    // Wave ws: o-tile ws*16.  Verified proj_out fragment code, B from LDS.
    {
        const int lr16 = lane & 15;
        const int lg16 = lane >> 4;
        const int ob   = ws * 16;

        f32x4 pacc[4];
#pragma unroll
        for (int i = 0; i < 4; ++i) pacc[i] = (f32x4){0.f, 0.f, 0.f, 0.f};

        for (int ks = 0; ks < 4; ++ks) {
            ushort8 a = *(const ushort8*)
                (wpf + (size_t)(ob + lr16) * DHV + ks * 32 + lg16 * 8);
#pragma unroll
            for (int qt = 0; qt < 4; ++qt) {
                ushort8 bfr = *(const ushort8*)
                    (olds + (qt * 16 + lr16) * 136 + ks * 32 + lg16 * 8);
                pacc[qt] = mfma16(a, bfr, pacc[qt]);
            }
        }

#pragma unroll
        for (int qt = 0; qt < 4; ++qt)
#pragma unroll
            for (int r = 0; r < 4; ++r) {
                int o = ob + lg16 * 4 + r;
                out[((size_t)b * CIN + o) * N_SP + q0 + qt * 16 + lr16]
                    = pacc[qt][r] + shiftp[o];
            }
    }
}

// ---------------------------------------------------------------------------
extern "C" void kernel_launch(void* const* d_in, const int* in_sizes, int n_in,
                              void* d_out, int out_size, void* d_ws, size_t ws_size,
                              hipStream_t stream)
{
    const float* x    = (const float*)d_in[0];
    const float* w_qk = (const float*)d_in[2];
    const float* g_qk = (const float*)d_in[3];
    const float* b_qk = (const float*)d_in[4];
    const float* m_qk = (const float*)d_in[5];
    const float* v_qk = (const float*)d_in[6];
    const float* w_v  = (const float*)d_in[7];
    const float* g_v  = (const float*)d_in[8];
    const float* b_v  = (const float*)d_in[9];
    const float* m_v  = (const float*)d_in[10];
    const float* v_v  = (const float*)d_in[11];
    const float* w_p  = (const float*)d_in[12];
    const float* g_p  = (const float*)d_in[13];
    const float* b_p  = (const float*)d_in[14];
    const float* m_p  = (const float*)d_in[15];
    const float* v_p  = (const float*)d_in[16];

    char* ws = (char*)d_ws;
    unsigned short* qkT = (unsigned short*)(ws);                    // 512 KB
    unsigned short* Vt  = (unsigned short*)(ws + (1u << 20));       // 4 MB
    unsigned short* wf1 = (unsigned short*)(ws + (9u << 20));       // 72 KB
    float* shift1       = (float*)(ws + (9u << 20) + 80 * 1024);    // 576 B
    unsigned short* wpf = (unsigned short*)(ws + (9u << 20) + 84 * 1024); // 64 KB
    float* shiftp       = (float*)(ws + (9u << 20) + 148 * 1024);   // 1 KB

    fold_weights<<<400, 256, 0, stream>>>(
        w_qk, g_qk, b_qk, m_qk, v_qk,
        w_v, g_v, b_v, m_v, v_v,
        w_p, g_p, b_p, m_p, v_p,
        wf1, shift1, wpf, shiftp);

    proj_qkv<<<dim3(64, 4), 512, 0, stream>>>(x, wf1, shift1, qkT, Vt);

    attn_kernel<<<dim3(64, 4), 1024, 0, stream>>>(
        qkT, Vt, wpf, shiftp, (float*)d_out);
}

// Round 16
// 71.776 us; speedup vs baseline: 1.0696x; 1.0696x over previous
//
#include <hip/hip_runtime.h>
#include <cstdint>
#include <cstddef>

// ---------------------------------------------------------------------------
// Attention_Param_sharing_Kv_sharing: B=4, C=256, H=W=64 (N=4096), KD=16,
// NH=8, DH=128.  Gram-matrix attention, one shared KV head.
//
// R14 (verified, 69.9us total / 53.6 attn): swapped 32x32x16 flash + fused
//   output projection, 64-key V tiles (128B rows = 4-way b128 floor).
// R15 REGRESSED (61.7 attn): 32-key tiles -> 64B rows -> 8-way V-read bank
//   conflict (10.5M vs 4.3M).  Occupancy 2x bought nothing: LDS pipe is the
//   binding resource, not latency.
// R16: attn reverted to R14 byte-for-byte.  proj_qkv (no barriers, pure
//   load-latency bound) -> 1024 thr / 16 waves = 4 n-subtiles x 4 o-groups
//   ({3,2,2,2} of 9 o-tiles), 4 waves/SIMD, zero LDS.
// ---------------------------------------------------------------------------

typedef __attribute__((ext_vector_type(4)))  float f32x4;
typedef __attribute__((ext_vector_type(16))) float f32x16;
typedef __attribute__((ext_vector_type(8)))  _Float16 half8;
typedef __attribute__((ext_vector_type(8)))  unsigned short ushort8;
typedef __attribute__((ext_vector_type(2)))  unsigned u32x2;
typedef __attribute__((ext_vector_type(4)))  unsigned u32x4;

#define N_SP 4096
#define CIN  256
#define KDIM 16
#define DHV  128

__device__ __forceinline__ unsigned short f2h(float f) {
    _Float16 h = (_Float16)f;             // RNE
    return __builtin_bit_cast(unsigned short, h);
}
__device__ __forceinline__ float h2f(unsigned short u) {
    return (float)__builtin_bit_cast(_Float16, u);
}
__device__ __forceinline__ unsigned pk2(float a, float b) {
    return (unsigned)f2h(a) | ((unsigned)f2h(b) << 16);
}
__device__ __forceinline__ unsigned shfl32u(unsigned v, int src) {
    return (unsigned)__shfl((int)v, src, 64);
}
__device__ __forceinline__ f32x4 mfma16(ushort8 a, ushort8 b, f32x4 c) {
    return __builtin_amdgcn_mfma_f32_16x16x32_f16(
        __builtin_bit_cast(half8, a), __builtin_bit_cast(half8, b), c, 0, 0, 0);
}
__device__ __forceinline__ f32x16 mfma32(half8 a, half8 b, f32x16 c) {
    return __builtin_amdgcn_mfma_f32_32x32x16_f16(a, b, c, 0, 0, 0);
}

// ---------------------------------------------------------------------------
// Kernel 0: fold BN into weights.  qk rows pre-scaled by sqrt(log2 e) so
// S arrives multiplied by log2(e) (exp2-domain softmax downstream).
// ---------------------------------------------------------------------------
__global__ __launch_bounds__(256) void fold_weights(
    const float* __restrict__ w_qk, const float* __restrict__ g_qk,
    const float* __restrict__ b_qk, const float* __restrict__ m_qk,
    const float* __restrict__ v_qk,
    const float* __restrict__ w_v, const float* __restrict__ g_v,
    const float* __restrict__ b_v, const float* __restrict__ m_v,
    const float* __restrict__ v_v,
    const float* __restrict__ w_p, const float* __restrict__ g_p,
    const float* __restrict__ b_p, const float* __restrict__ m_p,
    const float* __restrict__ v_p,
    unsigned short* __restrict__ wf1, float* __restrict__ shift1,
    unsigned short* __restrict__ wpf, float* __restrict__ shiftp)
{
    const float SQL2E = 1.2011224087864498f;   // sqrt(log2 e)
    int row = blockIdx.x;
    int t   = threadIdx.x;
    if (row < 144) {
        float s, sh; const float* src;
        if (row < KDIM) {
            s  = g_qk[row] * rsqrtf(v_qk[row] + 1e-5f);
            sh = b_qk[row] - m_qk[row] * s;
            s *= SQL2E; sh *= SQL2E;           // exp2-domain pre-scale
            src = w_qk + row * CIN;
        } else {
            int o = row - KDIM;
            s  = g_v[o] * rsqrtf(v_v[o] + 1e-5f);
            sh = b_v[o] - m_v[o] * s;
            src = w_v + o * CIN;
        }
        wf1[row * CIN + t] = f2h(src[t] * s);
        if (t == 0) shift1[row] = sh;
    } else {
        int o = row - 144;
        float s = g_p[o] * rsqrtf(v_p[o] + 1e-5f);
        if (t < DHV) wpf[o * DHV + t] = f2h(w_p[o * DHV + t] * s);
        if (t == 0) shiftp[o] = b_p[o] - m_p[o] * s;
    }
}

// ---------------------------------------------------------------------------
// Kernel 1: projection GEMM (x read once).  1024 thr = 16 waves =
// 4 n-subtiles x 4 o-groups ({3,2,2,2} of the 9 o-tiles); no barriers,
// no LDS -> 4 waves/SIMD of independent load-latency chains.
// ---------------------------------------------------------------------------
__global__ __launch_bounds__(1024) void proj_qkv(
    const float* __restrict__ x,
    const unsigned short* __restrict__ wf1, const float* __restrict__ shift1,
    unsigned short* __restrict__ qkT, unsigned short* __restrict__ Vt)
{
    const int b  = blockIdx.y;
    const int n0 = blockIdx.x * 64;
    const int tid  = threadIdx.x;
    const int w    = tid >> 6;
    const int nq   = w & 3;            // n-subtile 0..3
    const int og   = w >> 2;           // o-group 0..3
    const int lane = tid & 63;
    const int lg   = lane >> 4;
    const int lr   = lane & 15;
    const int n    = n0 + nq * 16 + lr;

    const int tstart = (og == 0) ? 0 : (og * 2 + 1);   // {0,3,5,7}
    const int tcnt   = (og == 0) ? 3 : 2;

    const float* xb = x + (size_t)b * CIN * N_SP;

    f32x4 acc[3];
#pragma unroll
    for (int i = 0; i < 3; ++i) acc[i] = (f32x4){0.f, 0.f, 0.f, 0.f};

    for (int ks = 0; ks < 8; ++ks) {
        const int cbase = ks * 32 + lg * 8;
        ushort8 bx;
#pragma unroll
        for (int j = 0; j < 8; ++j)
            bx[j] = f2h(xb[(size_t)(cbase + j) * N_SP + n]);
#pragma unroll
        for (int i = 0; i < 3; ++i) {
            if (i < tcnt) {
                ushort8 a = *(const ushort8*)
                    (wf1 + ((tstart + i) * 16 + lr) * CIN + cbase);
                acc[i] = mfma16(a, bx, acc[i]);
            }
        }
    }

#pragma unroll
    for (int i = 0; i < 3; ++i) {
        if (i < tcnt) {
#pragma unroll
            for (int r = 0; r < 4; ++r) {
                int o = (tstart + i) * 16 + lg * 4 + r;
                float val = acc[i][r] + shift1[o];
                unsigned short hv = f2h(val);
                if (o < KDIM) qkT[((size_t)b * N_SP + n) * 16 + o] = hv;
                else          Vt[((size_t)b * DHV + (o - KDIM)) * N_SP + n] = hv;
            }
        }
    }
}

// ---------------------------------------------------------------------------
// Stage one 64-key V tile (128 d x 64 halves = 16 KB) via global_load_lds,
// 16 x 1KB chunks; wave p of the stream issues chunks [p*8, p*8+8).
// Source pre-swizzled (rule 21): physical 16B slot s of row d holds
// logical slot s ^ (d&7).
// ---------------------------------------------------------------------------
__device__ __forceinline__ void stage_v(
    const unsigned short* __restrict__ vt_b,
    unsigned short* v_l, int k0, int p, int lane)
{
#pragma unroll
    for (int s = 0; s < 8; ++s) {
        const int vi = p * 8 + s;
        const int d  = vi * 8 + (lane >> 3);
        const int c8 = (lane & 7) ^ ((lane >> 3) & 7);
        const unsigned short* src = vt_b + (size_t)d * N_SP + k0 + c8 * 8;
        __builtin_amdgcn_global_load_lds(
            (const __attribute__((address_space(1))) void*)src,
            (__attribute__((address_space(3))) void*)(v_l + vi * 512),
            16, 0, 0);
    }
}

// V A-frag for PV: A[m=d][k]: lane&31 = d-row, k = (lane>>5)*8 + j.
__device__ __forceinline__ half8 ldv(const unsigned short* vl, int nb, int kc,
                                     int la31, int hi)
{
    const int d = nb * 32 + la31;
    const ushort8 v = *(const ushort8*)
        (vl + d * 64 + (((kc * 2 + hi) ^ (d & 7)) << 3));
    return __builtin_bit_cast(half8, v);
}

// K A-frag for S: A[m=key][k]: lane&31 = key-row, k = (lane>>5)*8 + j.
__device__ __forceinline__ half8 ldk(const unsigned short* qk_b, int krow,
                                     int la31, int hi)
{
    return __builtin_bit_cast(half8,
        *(const ushort8*)(qk_b + (size_t)(krow + la31) * 16 + hi * 8));
}

// ---------------------------------------------------------------------------
// Kernel 2: flash attention + fused output projection (verified R14).
// Grid (64, B), 512 thr = 8 waves = 4 streams x 2 waves.  Stream s: keys
// [s*1024,(s+1)*1024), wave p of stream: queries q0+p*32 .. +31.
// ---------------------------------------------------------------------------
__global__ __launch_bounds__(512, 2) void attn_kernel(
    const unsigned short* __restrict__ qkT,   // [b][n][16] f16 (x sqrt(log2e))
    const unsigned short* __restrict__ Vt,    // [b][128][n] f16
    const unsigned short* __restrict__ wpf,   // [256][128] f16
    const float* __restrict__ shiftp,         // [256] f32
    float* __restrict__ out)                  // [b][256][4096] f32
{
    const int b  = blockIdx.y;
    const int q0 = blockIdx.x * 64;
    const int tid  = threadIdx.x;
    const int ws   = tid >> 6;
    const int strm = ws >> 1;          // key-stream 0..3
    const int p    = ws & 1;           // q-half 0..1
    const int lane = tid & 63;
    const int la31 = lane & 31;
    const int hi   = lane >> 5;

    const unsigned short* qk_b = qkT + (size_t)b * N_SP * 16;
    const unsigned short* vt_b = Vt  + (size_t)b * DHV * N_SP;
    const int kbase = strm * (N_SP / 4);
    const int qrow  = q0 + p * 32;

    // Q B-frag (col n = query = lane&31, k = hi*8+j)
    const half8 aq = __builtin_bit_cast(half8,
        *(const ushort8*)(qk_b + (size_t)(qrow + la31) * 16 + hi * 8));

    f32x16 acc0, acc1, acc2, acc3, z16;
#pragma unroll
    for (int i = 0; i < 16; ++i) { z16[i] = 0.f; }
    acc0 = z16; acc1 = z16; acc2 = z16; acc3 = z16;
    float m_r = -__builtin_inff();
    float l_r = 0.f;

    __shared__ __align__(16) unsigned short v_lds[4][2][128 * 64];  // 128 KB
    __shared__ float lmbuf[4][64][2];                               // 2 KB

    stage_v(vt_b, &v_lds[strm][0][0], kbase, p, lane);
    // K register prefetch for tile 0
    half8 kf0n = ldk(qk_b, kbase, la31, hi);
    half8 kf1n = ldk(qk_b, kbase + 32, la31, hi);

    for (int t = 0; t < 16; ++t) {
        const int cur = t & 1;
        __syncthreads();            // buf[cur] + kf*n ready; prior reads done
        if (t < 15)
            stage_v(vt_b, &v_lds[strm][cur ^ 1][0], kbase + (t + 1) * 64,
                    p, lane);
        const half8 kf0 = kf0n;
        const half8 kf1 = kf1n;
        if (t < 15) {               // prefetch K for tile t+1
            kf0n = ldk(qk_b, kbase + (t + 1) * 64, la31, hi);
            kf1n = ldk(qk_b, kbase + (t + 1) * 64 + 32, la31, hi);
        }
        const unsigned short* vl = &v_lds[strm][cur][0];

        // ---- S' = (K Q^T) * log2e (pre-scaled weights) --------------------
        f32x16 s0 = mfma32(kf0, aq, z16);     // keys k0..k0+31
        f32x16 s1 = mfma32(kf1, aq, z16);     // keys k0+32..k0+63

        // ---- in-lane softmax, 2-domain ------------------------------------
        float mpair[8];
#pragma unroll
        for (int i = 0; i < 8; ++i)
            mpair[i] = fmaxf(fmaxf(s0[i], s0[i + 8]), fmaxf(s1[i], s1[i + 8]));
        float mx = fmaxf(fmaxf(fmaxf(mpair[0], mpair[1]), fmaxf(mpair[2], mpair[3])),
                         fmaxf(fmaxf(mpair[4], mpair[5]), fmaxf(mpair[6], mpair[7])));
        mx = fmaxf(mx, __shfl(mx, lane ^ 32));   // other 32 keys on lane^32

        // defer-max: THR = 8*log2e = 11.54 (P <= 2^11.54 = e^8, fp16-safe)
        if (!__all(mx <= m_r + 11.54f)) {
            float mnew = fmaxf(m_r, mx);
            float sc = exp2f(m_r - mnew);         // first tile: exp2(-inf)=0
            l_r *= sc;
#pragma unroll
            for (int i = 0; i < 16; ++i) {
                acc0[i] *= sc; acc1[i] *= sc; acc2[i] *= sc; acc3[i] *= sc;
            }
            m_r = mnew;
        }
#pragma unroll
        for (int i = 0; i < 16; ++i) s0[i] = exp2f(s0[i] - m_r);
#pragma unroll
        for (int i = 0; i < 16; ++i) s1[i] = exp2f(s1[i] - m_r);
        float rpair[8];
#pragma unroll
        for (int i = 0; i < 8; ++i)
            rpair[i] = (s0[i] + s0[i + 8]) + (s1[i] + s1[i + 8]);
        l_r += ((rpair[0] + rpair[1]) + (rpair[2] + rpair[3]))
             + ((rpair[4] + rpair[5]) + (rpair[6] + rpair[7]));

        // ---- O += V^T P : A = V (m=d), B = P (n=query) --------------------
#define PV_CHUNK(SV, B0, KC)                                               \
        {                                                                  \
            unsigned a0 = pk2(SV[B0 + 0], SV[B0 + 1]);                     \
            unsigned a1 = pk2(SV[B0 + 2], SV[B0 + 3]);                     \
            unsigned a2 = pk2(SV[B0 + 4], SV[B0 + 5]);                     \
            unsigned a3 = pk2(SV[B0 + 6], SV[B0 + 7]);                     \
            unsigned p0 = shfl32u(a0, lane ^ 32);                          \
            unsigned p1 = shfl32u(a1, lane ^ 32);                          \
            unsigned p2 = shfl32u(a2, lane ^ 32);                          \
            unsigned p3 = shfl32u(a3, lane ^ 32);                          \
            u32x4 pw;                                                      \
            pw.x = hi ? p2 : a0;                                           \
            pw.y = hi ? p3 : a1;                                           \
            pw.z = hi ? a2 : p0;                                           \
            pw.w = hi ? a3 : p1;                                           \
            half8 pb = __builtin_bit_cast(half8, pw);                      \
            acc0 = mfma32(ldv(vl, 0, KC, la31, hi), pb, acc0);             \
            acc1 = mfma32(ldv(vl, 1, KC, la31, hi), pb, acc1);             \
            acc2 = mfma32(ldv(vl, 2, KC, la31, hi), pb, acc2);             \
            acc3 = mfma32(ldv(vl, 3, KC, la31, hi), pb, acc3);             \
        }
        PV_CHUNK(s0, 0, 0)
        PV_CHUNK(s0, 8, 1)
        PV_CHUNK(s1, 0, 2)
        PV_CHUNK(s1, 8, 3)
#undef PV_CHUNK
    }

    // ---- finish l: other half of the keys lives on lane^32 ---------------
    l_r = l_r + __shfl(l_r, lane ^ 32);

    __syncthreads();   // all streams done reading V bufs -> safe to reuse

    // ---- publish normalized partial O (fp16) + (m,l) ---------------------
    unsigned short* Opart = &v_lds[0][0][0];  // [4 streams][64 q][128 d] f16
    const int qib = p * 32 + la31;
    if (hi == 0) {
        lmbuf[strm][qib][0] = m_r;
        lmbuf[strm][qib][1] = l_r;
    }
    {
        const float invl = 1.0f / l_r;
        const size_t qoff = ((size_t)strm * 64 + qib) * 128;
#define PUB(ACC, NB)                                                       \
        {                                                                  \
            _Pragma("unroll")                                              \
            for (int rq = 0; rq < 4; ++rq) {                               \
                float v0 = ACC[rq * 4 + 0] * invl;                         \
                float v1 = ACC[rq * 4 + 1] * invl;                         \
                float v2 = ACC[rq * 4 + 2] * invl;                         \
                float v3 = ACC[rq * 4 + 3] * invl;                         \
                u32x2 wv; wv.x = pk2(v0, v1); wv.y = pk2(v2, v3);          \
                *(u32x2*)(Opart + qoff + NB * 32 + rq * 8 + 4 * hi) = wv;  \
            }                                                              \
        }
        PUB(acc0, 0) PUB(acc1, 1) PUB(acc2, 2) PUB(acc3, 3)
#undef PUB
    }
    __syncthreads();

    // ---- merge 4 streams -> olds[64][136] f16 (272B stride: 2-way banks) --
    unsigned short* olds = &v_lds[2][0][0];   // 17.4 KB, dead V region
    {
        const int q    = tid >> 3;
        const int dseg = (tid & 7) * 16;
        const float m0 = lmbuf[0][q][0], l0 = lmbuf[0][q][1];
        const float m1 = lmbuf[1][q][0], l1 = lmbuf[1][q][1];
        const float m2 = lmbuf[2][q][0], l2 = lmbuf[2][q][1];
        const float m3 = lmbuf[3][q][0], l3 = lmbuf[3][q][1];
        const float M = fmaxf(fmaxf(m0, m1), fmaxf(m2, m3));
        float w0 = l0 * exp2f(m0 - M);
        float w1 = l1 * exp2f(m1 - M);
        float w2 = l2 * exp2f(m2 - M);
        float w3 = l3 * exp2f(m3 - M);
        const float inv = 1.0f / (w0 + w1 + w2 + w3);
        w0 *= inv; w1 *= inv; w2 *= inv; w3 *= inv;

        const ushort8 A0 = *(const ushort8*)(Opart + (0 * 64 + q) * 128 + dseg);
        const ushort8 A1 = *(const ushort8*)(Opart + (1 * 64 + q) * 128 + dseg);
        const ushort8 A2 = *(const ushort8*)(Opart + (2 * 64 + q) * 128 + dseg);
        const ushort8 A3 = *(const ushort8*)(Opart + (3 * 64 + q) * 128 + dseg);
        const ushort8 B0 = *(const ushort8*)(Opart + (0 * 64 + q) * 128 + dseg + 8);
        const ushort8 B1 = *(const ushort8*)(Opart + (1 * 64 + q) * 128 + dseg + 8);
        const ushort8 B2 = *(const ushort8*)(Opart + (2 * 64 + q) * 128 + dseg + 8);
        const ushort8 B3 = *(const ushort8*)(Opart + (3 * 64 + q) * 128 + dseg + 8);

        ushort8 o0, o1;
#pragma unroll
        for (int i = 0; i < 8; ++i) {
            float va = w0 * h2f(A0[i]) + w1 * h2f(A1[i])
                     + w2 * h2f(A2[i]) + w3 * h2f(A3[i]);
            float vb = w0 * h2f(B0[i]) + w1 * h2f(B1[i])
                     + w2 * h2f(B2[i]) + w3 * h2f(B3[i]);
            o0[i] = f2h(fmaxf(va, 0.f));    // relu
            o1[i] = f2h(fmaxf(vb, 0.f));
        }
        *(ushort8*)(olds + q * 136 + dseg)     = o0;
        *(ushort8*)(olds + q * 136 + dseg + 8) = o1;
    }
    __syncthreads();

    // ---- fused output projection: out[b][256][q0..q0+64) ------------------
    {
        const int lr16 = lane & 15;
        const int lg16 = lane >> 4;
        const int ob   = ws * 32;

        f32x4 pacc[2][4];
#pragma unroll
        for (int i = 0; i < 2; ++i)
#pragma unroll
            for (int j = 0; j < 4; ++j) pacc[i][j] = (f32x4){0.f, 0.f, 0.f, 0.f};

        for (int ks = 0; ks < 4; ++ks) {
            ushort8 a0 = *(const ushort8*)
                (wpf + (size_t)(ob + lr16) * DHV + ks * 32 + lg16 * 8);
            ushort8 a1 = *(const ushort8*)
                (wpf + (size_t)(ob + 16 + lr16) * DHV + ks * 32 + lg16 * 8);
#pragma unroll
            for (int qt = 0; qt < 4; ++qt) {
                ushort8 bfr = *(const ushort8*)
                    (olds + (qt * 16 + lr16) * 136 + ks * 32 + lg16 * 8);
                pacc[0][qt] = mfma16(a0, bfr, pacc[0][qt]);
                pacc[1][qt] = mfma16(a1, bfr, pacc[1][qt]);
            }
        }

#pragma unroll
        for (int t2 = 0; t2 < 2; ++t2)
#pragma unroll
            for (int qt = 0; qt < 4; ++qt)
#pragma unroll
                for (int r = 0; r < 4; ++r) {
                    int o = ob + t2 * 16 + lg16 * 4 + r;
                    out[((size_t)b * CIN + o) * N_SP + q0 + qt * 16 + lr16]
                        = pacc[t2][qt][r] + shiftp[o];
                }
    }
}

// ---------------------------------------------------------------------------
extern "C" void kernel_launch(void* const* d_in, const int* in_sizes, int n_in,
                              void* d_out, int out_size, void* d_ws, size_t ws_size,
                              hipStream_t stream)
{
    const float* x    = (const float*)d_in[0];
    const float* w_qk = (const float*)d_in[2];
    const float* g_qk = (const float*)d_in[3];
    const float* b_qk = (const float*)d_in[4];
    const float* m_qk = (const float*)d_in[5];
    const float* v_qk = (const float*)d_in[6];
    const float* w_v  = (const float*)d_in[7];
    const float* g_v  = (const float*)d_in[8];
    const float* b_v  = (const float*)d_in[9];
    const float* m_v  = (const float*)d_in[10];
    const float* v_v  = (const float*)d_in[11];
    const float* w_p  = (const float*)d_in[12];
    const float* g_p  = (const float*)d_in[13];
    const float* b_p  = (const float*)d_in[14];
    const float* m_p  = (const float*)d_in[15];
    const float* v_p  = (const float*)d_in[16];

    char* ws = (char*)d_ws;
    unsigned short* qkT = (unsigned short*)(ws);                    // 512 KB
    unsigned short* Vt  = (unsigned short*)(ws + (1u << 20));       // 4 MB
    unsigned short* wf1 = (unsigned short*)(ws + (9u << 20));       // 72 KB
    float* shift1       = (float*)(ws + (9u << 20) + 80 * 1024);    // 576 B
    unsigned short* wpf = (unsigned short*)(ws + (9u << 20) + 84 * 1024); // 64 KB
    float* shiftp       = (float*)(ws + (9u << 20) + 148 * 1024);   // 1 KB

    fold_weights<<<400, 256, 0, stream>>>(
        w_qk, g_qk, b_qk, m_qk, v_qk,
        w_v, g_v, b_v, m_v, v_v,
        w_p, g_p, b_p, m_p, v_p,
        wf1, shift1, wpf, shiftp);

    proj_qkv<<<dim3(64, 4), 1024, 0, stream>>>(x, wf1, shift1, qkT, Vt);

    attn_kernel<<<dim3(64, 4), 512, 0, stream>>>(
        qkT, Vt, wpf, shiftp, (float*)d_out);
}

// Round 17
// 69.967 us; speedup vs baseline: 1.0972x; 1.0258x over previous
//
#include <hip/hip_runtime.h>
#include <cstdint>
#include <cstddef>

// ---------------------------------------------------------------------------
// Attention_Param_sharing_Kv_sharing: B=4, C=256, H=W=64 (N=4096), KD=16,
// NH=8, DH=128.  Gram-matrix attention, one shared KV head.
//
// FINAL (R17) = best-known verified configuration:
//   - attn: R14 swapped-32x32x16 flash + fused output projection
//     (in-lane softmax, P in registers, defer-max THR=8*log2e, exp2-domain,
//     K-reg prefetch, 64-key V tiles = 4-way b128 floor).  53.7 us.
//   - proj_qkv: R14 512-thr 5/4 o-split (R16's 1024-thr variant regressed).
//   History: R4 175us -> R8 LDS-shared staging 138 -> R9 8-wave 101.6 ->
//   R12 swapped-32x32 79.1 -> R13 +prefetch/defer-max 72.0 -> R14 fused 69.9.
//   Failed directions (kept out): global key-split (R5, L2 flush), 32-key
//   V tiles (R15, 8-way conflicts), 1024-thr proj_qkv (R16).
// ---------------------------------------------------------------------------

typedef __attribute__((ext_vector_type(4)))  float f32x4;
typedef __attribute__((ext_vector_type(16))) float f32x16;
typedef __attribute__((ext_vector_type(8)))  _Float16 half8;
typedef __attribute__((ext_vector_type(8)))  unsigned short ushort8;
typedef __attribute__((ext_vector_type(2)))  unsigned u32x2;
typedef __attribute__((ext_vector_type(4)))  unsigned u32x4;

#define N_SP 4096
#define CIN  256
#define KDIM 16
#define DHV  128

__device__ __forceinline__ unsigned short f2h(float f) {
    _Float16 h = (_Float16)f;             // RNE
    return __builtin_bit_cast(unsigned short, h);
}
__device__ __forceinline__ float h2f(unsigned short u) {
    return (float)__builtin_bit_cast(_Float16, u);
}
__device__ __forceinline__ unsigned pk2(float a, float b) {
    return (unsigned)f2h(a) | ((unsigned)f2h(b) << 16);
}
__device__ __forceinline__ unsigned shfl32u(unsigned v, int src) {
    return (unsigned)__shfl((int)v, src, 64);
}
__device__ __forceinline__ f32x4 mfma16(ushort8 a, ushort8 b, f32x4 c) {
    return __builtin_amdgcn_mfma_f32_16x16x32_f16(
        __builtin_bit_cast(half8, a), __builtin_bit_cast(half8, b), c, 0, 0, 0);
}
__device__ __forceinline__ f32x16 mfma32(half8 a, half8 b, f32x16 c) {
    return __builtin_amdgcn_mfma_f32_32x32x16_f16(a, b, c, 0, 0, 0);
}

// ---------------------------------------------------------------------------
// Kernel 0: fold BN into weights.  qk rows pre-scaled by sqrt(log2 e) so
// S arrives multiplied by log2(e) (exp2-domain softmax downstream).
// ---------------------------------------------------------------------------
__global__ __launch_bounds__(256) void fold_weights(
    const float* __restrict__ w_qk, const float* __restrict__ g_qk,
    const float* __restrict__ b_qk, const float* __restrict__ m_qk,
    const float* __restrict__ v_qk,
    const float* __restrict__ w_v, const float* __restrict__ g_v,
    const float* __restrict__ b_v, const float* __restrict__ m_v,
    const float* __restrict__ v_v,
    const float* __restrict__ w_p, const float* __restrict__ g_p,
    const float* __restrict__ b_p, const float* __restrict__ m_p,
    const float* __restrict__ v_p,
    unsigned short* __restrict__ wf1, float* __restrict__ shift1,
    unsigned short* __restrict__ wpf, float* __restrict__ shiftp)
{
    const float SQL2E = 1.2011224087864498f;   // sqrt(log2 e)
    int row = blockIdx.x;
    int t   = threadIdx.x;
    if (row < 144) {
        float s, sh; const float* src;
        if (row < KDIM) {
            s  = g_qk[row] * rsqrtf(v_qk[row] + 1e-5f);
            sh = b_qk[row] - m_qk[row] * s;
            s *= SQL2E; sh *= SQL2E;           // exp2-domain pre-scale
            src = w_qk + row * CIN;
        } else {
            int o = row - KDIM;
            s  = g_v[o] * rsqrtf(v_v[o] + 1e-5f);
            sh = b_v[o] - m_v[o] * s;
            src = w_v + o * CIN;
        }
        wf1[row * CIN + t] = f2h(src[t] * s);
        if (t == 0) shift1[row] = sh;
    } else {
        int o = row - 144;
        float s = g_p[o] * rsqrtf(v_p[o] + 1e-5f);
        if (t < DHV) wpf[o * DHV + t] = f2h(w_p[o * DHV + t] * s);
        if (t == 0) shiftp[o] = b_p[o] - m_p[o] * s;
    }
}

// ---------------------------------------------------------------------------
// Kernel 1: projection GEMM (x read once).  512 thr = 8 waves; wave-halves
// split the 9 o-tiles 5/4 (verified R14 configuration).
// ---------------------------------------------------------------------------
__global__ __launch_bounds__(512) void proj_qkv(
    const float* __restrict__ x,
    const unsigned short* __restrict__ wf1, const float* __restrict__ shift1,
    unsigned short* __restrict__ qkT, unsigned short* __restrict__ Vt)
{
    const int b  = blockIdx.y;
    const int n0 = blockIdx.x * 64;
    const int tid  = threadIdx.x;
    const int w    = tid >> 6;
    const int half = w >> 2;           // o-half: 0 -> ot 0..4, 1 -> ot 5..8
    const int wq   = w & 3;            // n-subtile
    const int lane = tid & 63;
    const int lg   = lane >> 4;
    const int lr   = lane & 15;
    const int n    = n0 + wq * 16 + lr;

    const float* xb = x + (size_t)b * CIN * N_SP;

    if (half == 0) {
        f32x4 acc[5];
#pragma unroll
        for (int i = 0; i < 5; ++i) acc[i] = (f32x4){0.f, 0.f, 0.f, 0.f};
        for (int ks = 0; ks < 8; ++ks) {
            const int cbase = ks * 32 + lg * 8;
            ushort8 bx;
#pragma unroll
            for (int j = 0; j < 8; ++j)
                bx[j] = f2h(xb[(size_t)(cbase + j) * N_SP + n]);
#pragma unroll
            for (int i = 0; i < 5; ++i) {
                ushort8 a = *(const ushort8*)(wf1 + (i * 16 + lr) * CIN + cbase);
                acc[i] = mfma16(a, bx, acc[i]);
            }
        }
#pragma unroll
        for (int i = 0; i < 5; ++i)
#pragma unroll
            for (int r = 0; r < 4; ++r) {
                int o = i * 16 + lg * 4 + r;
                float val = acc[i][r] + shift1[o];
                unsigned short hv = f2h(val);
                if (o < KDIM) qkT[((size_t)b * N_SP + n) * 16 + o] = hv;
                else          Vt[((size_t)b * DHV + (o - KDIM)) * N_SP + n] = hv;
            }
    } else {
        f32x4 acc[4];
#pragma unroll
        for (int i = 0; i < 4; ++i) acc[i] = (f32x4){0.f, 0.f, 0.f, 0.f};
        for (int ks = 0; ks < 8; ++ks) {
            const int cbase = ks * 32 + lg * 8;
            ushort8 bx;
#pragma unroll
            for (int j = 0; j < 8; ++j)
                bx[j] = f2h(xb[(size_t)(cbase + j) * N_SP + n]);
#pragma unroll
            for (int i = 0; i < 4; ++i) {
                ushort8 a = *(const ushort8*)(wf1 + ((i + 5) * 16 + lr) * CIN + cbase);
                acc[i] = mfma16(a, bx, acc[i]);
            }
        }
#pragma unroll
        for (int i = 0; i < 4; ++i)
#pragma unroll
            for (int r = 0; r < 4; ++r) {
                int o = (i + 5) * 16 + lg * 4 + r;
                float val = acc[i][r] + shift1[o];
                Vt[((size_t)b * DHV + (o - KDIM)) * N_SP + n] = f2h(val);
            }
    }
}

// ---------------------------------------------------------------------------
// Stage one 64-key V tile (128 d x 64 halves = 16 KB) via global_load_lds,
// 16 x 1KB chunks; wave p of the stream issues chunks [p*8, p*8+8).
// Source pre-swizzled (rule 21): physical 16B slot s of row d holds
// logical slot s ^ (d&7).
// ---------------------------------------------------------------------------
__device__ __forceinline__ void stage_v(
    const unsigned short* __restrict__ vt_b,
    unsigned short* v_l, int k0, int p, int lane)
{
#pragma unroll
    for (int s = 0; s < 8; ++s) {
        const int vi = p * 8 + s;
        const int d  = vi * 8 + (lane >> 3);
        const int c8 = (lane & 7) ^ ((lane >> 3) & 7);
        const unsigned short* src = vt_b + (size_t)d * N_SP + k0 + c8 * 8;
        __builtin_amdgcn_global_load_lds(
            (const __attribute__((address_space(1))) void*)src,
            (__attribute__((address_space(3))) void*)(v_l + vi * 512),
            16, 0, 0);
    }
}

// V A-frag for PV: A[m=d][k]: lane&31 = d-row, k = (lane>>5)*8 + j.
__device__ __forceinline__ half8 ldv(const unsigned short* vl, int nb, int kc,
                                     int la31, int hi)
{
    const int d = nb * 32 + la31;
    const ushort8 v = *(const ushort8*)
        (vl + d * 64 + (((kc * 2 + hi) ^ (d & 7)) << 3));
    return __builtin_bit_cast(half8, v);
}

// K A-frag for S: A[m=key][k]: lane&31 = key-row, k = (lane>>5)*8 + j.
__device__ __forceinline__ half8 ldk(const unsigned short* qk_b, int krow,
                                     int la31, int hi)
{
    return __builtin_bit_cast(half8,
        *(const ushort8*)(qk_b + (size_t)(krow + la31) * 16 + hi * 8));
}

// ---------------------------------------------------------------------------
// Kernel 2: flash attention + fused output projection (verified R14).
// Grid (64, B), 512 thr = 8 waves = 4 streams x 2 waves.  Stream s: keys
// [s*1024,(s+1)*1024), wave p of stream: queries q0+p*32 .. +31.
// ---------------------------------------------------------------------------
__global__ __launch_bounds__(512, 2) void attn_kernel(
    const unsigned short* __restrict__ qkT,   // [b][n][16] f16 (x sqrt(log2e))
    const unsigned short* __restrict__ Vt,    // [b][128][n] f16
    const unsigned short* __restrict__ wpf,   // [256][128] f16
    const float* __restrict__ shiftp,         // [256] f32
    float* __restrict__ out)                  // [b][256][4096] f32
{
    const int b  = blockIdx.y;
    const int q0 = blockIdx.x * 64;
    const int tid  = threadIdx.x;
    const int ws   = tid >> 6;
    const int strm = ws >> 1;          // key-stream 0..3
    const int p    = ws & 1;           // q-half 0..1
    const int lane = tid & 63;
    const int la31 = lane & 31;
    const int hi   = lane >> 5;

    const unsigned short* qk_b = qkT + (size_t)b * N_SP * 16;
    const unsigned short* vt_b = Vt  + (size_t)b * DHV * N_SP;
    const int kbase = strm * (N_SP / 4);
    const int qrow  = q0 + p * 32;

    // Q B-frag (col n = query = lane&31, k = hi*8+j)
    const half8 aq = __builtin_bit_cast(half8,
        *(const ushort8*)(qk_b + (size_t)(qrow + la31) * 16 + hi * 8));

    f32x16 acc0, acc1, acc2, acc3, z16;
#pragma unroll
    for (int i = 0; i < 16; ++i) { z16[i] = 0.f; }
    acc0 = z16; acc1 = z16; acc2 = z16; acc3 = z16;
    float m_r = -__builtin_inff();
    float l_r = 0.f;

    __shared__ __align__(16) unsigned short v_lds[4][2][128 * 64];  // 128 KB
    __shared__ float lmbuf[4][64][2];                               // 2 KB

    stage_v(vt_b, &v_lds[strm][0][0], kbase, p, lane);
    // K register prefetch for tile 0
    half8 kf0n = ldk(qk_b, kbase, la31, hi);
    half8 kf1n = ldk(qk_b, kbase + 32, la31, hi);

    for (int t = 0; t < 16; ++t) {
        const int cur = t & 1;
        __syncthreads();            // buf[cur] + kf*n ready; prior reads done
        if (t < 15)
            stage_v(vt_b, &v_lds[strm][cur ^ 1][0], kbase + (t + 1) * 64,
                    p, lane);
        const half8 kf0 = kf0n;
        const half8 kf1 = kf1n;
        if (t < 15) {               // prefetch K for tile t+1
            kf0n = ldk(qk_b, kbase + (t + 1) * 64, la31, hi);
            kf1n = ldk(qk_b, kbase + (t + 1) * 64 + 32, la31, hi);
        }
        const unsigned short* vl = &v_lds[strm][cur][0];

        // ---- S' = (K Q^T) * log2e (pre-scaled weights) --------------------
        f32x16 s0 = mfma32(kf0, aq, z16);     // keys k0..k0+31
        f32x16 s1 = mfma32(kf1, aq, z16);     // keys k0+32..k0+63

        // ---- in-lane softmax, 2-domain ------------------------------------
        float mpair[8];
#pragma unroll
        for (int i = 0; i < 8; ++i)
            mpair[i] = fmaxf(fmaxf(s0[i], s0[i + 8]), fmaxf(s1[i], s1[i + 8]));
        float mx = fmaxf(fmaxf(fmaxf(mpair[0], mpair[1]), fmaxf(mpair[2], mpair[3])),
                         fmaxf(fmaxf(mpair[4], mpair[5]), fmaxf(mpair[6], mpair[7])));
        mx = fmaxf(mx, __shfl(mx, lane ^ 32));   // other 32 keys on lane^32

        // defer-max: THR = 8*log2e = 11.54 (P <= 2^11.54 = e^8, fp16-safe)
        if (!__all(mx <= m_r + 11.54f)) {
            float mnew = fmaxf(m_r, mx);
            float sc = exp2f(m_r - mnew);         // first tile: exp2(-inf)=0
            l_r *= sc;
#pragma unroll
            for (int i = 0; i < 16; ++i) {
                acc0[i] *= sc; acc1[i] *= sc; acc2[i] *= sc; acc3[i] *= sc;
            }
            m_r = mnew;
        }
#pragma unroll
        for (int i = 0; i < 16; ++i) s0[i] = exp2f(s0[i] - m_r);
#pragma unroll
        for (int i = 0; i < 16; ++i) s1[i] = exp2f(s1[i] - m_r);
        float rpair[8];
#pragma unroll
        for (int i = 0; i < 8; ++i)
            rpair[i] = (s0[i] + s0[i + 8]) + (s1[i] + s1[i + 8]);
        l_r += ((rpair[0] + rpair[1]) + (rpair[2] + rpair[3]))
             + ((rpair[4] + rpair[5]) + (rpair[6] + rpair[7]));

        // ---- O += V^T P : A = V (m=d), B = P (n=query) --------------------
#define PV_CHUNK(SV, B0, KC)                                               \
        {                                                                  \
            unsigned a0 = pk2(SV[B0 + 0], SV[B0 + 1]);                     \
            unsigned a1 = pk2(SV[B0 + 2], SV[B0 + 3]);                     \
            unsigned a2 = pk2(SV[B0 + 4], SV[B0 + 5]);                     \
            unsigned a3 = pk2(SV[B0 + 6], SV[B0 + 7]);                     \
            unsigned p0 = shfl32u(a0, lane ^ 32);                          \
            unsigned p1 = shfl32u(a1, lane ^ 32);                          \
            unsigned p2 = shfl32u(a2, lane ^ 32);                          \
            unsigned p3 = shfl32u(a3, lane ^ 32);                          \
            u32x4 pw;                                                      \
            pw.x = hi ? p2 : a0;                                           \
            pw.y = hi ? p3 : a1;                                           \
            pw.z = hi ? a2 : p0;                                           \
            pw.w = hi ? a3 : p1;                                           \
            half8 pb = __builtin_bit_cast(half8, pw);                      \
            acc0 = mfma32(ldv(vl, 0, KC, la31, hi), pb, acc0);             \
            acc1 = mfma32(ldv(vl, 1, KC, la31, hi), pb, acc1);             \
            acc2 = mfma32(ldv(vl, 2, KC, la31, hi), pb, acc2);             \
            acc3 = mfma32(ldv(vl, 3, KC, la31, hi), pb, acc3);             \
        }
        PV_CHUNK(s0, 0, 0)
        PV_CHUNK(s0, 8, 1)
        PV_CHUNK(s1, 0, 2)
        PV_CHUNK(s1, 8, 3)
#undef PV_CHUNK
    }

    // ---- finish l: other half of the keys lives on lane^32 ---------------
    l_r = l_r + __shfl(l_r, lane ^ 32);

    __syncthreads();   // all streams done reading V bufs -> safe to reuse

    // ---- publish normalized partial O (fp16) + (m,l) ---------------------
    unsigned short* Opart = &v_lds[0][0][0];  // [4 streams][64 q][128 d] f16
    const int qib = p * 32 + la31;
    if (hi == 0) {
        lmbuf[strm][qib][0] = m_r;
        lmbuf[strm][qib][1] = l_r;
    }
    {
        const float invl = 1.0f / l_r;
        const size_t qoff = ((size_t)strm * 64 + qib) * 128;
#define PUB(ACC, NB)                                                       \
        {                                                                  \
            _Pragma("unroll")                                              \
            for (int rq = 0; rq < 4; ++rq) {                               \
                float v0 = ACC[rq * 4 + 0] * invl;                         \
                float v1 = ACC[rq * 4 + 1] * invl;                         \
                float v2 = ACC[rq * 4 + 2] * invl;                         \
                float v3 = ACC[rq * 4 + 3] * invl;                         \
                u32x2 wv; wv.x = pk2(v0, v1); wv.y = pk2(v2, v3);          \
                *(u32x2*)(Opart + qoff + NB * 32 + rq * 8 + 4 * hi) = wv;  \
            }                                                              \
        }
        PUB(acc0, 0) PUB(acc1, 1) PUB(acc2, 2) PUB(acc3, 3)
#undef PUB
    }
    __syncthreads();

    // ---- merge 4 streams -> olds[64][136] f16 (272B stride: 2-way banks) --
    unsigned short* olds = &v_lds[2][0][0];   // 17.4 KB, dead V region
    {
        const int q    = tid >> 3;
        const int dseg = (tid & 7) * 16;
        const float m0 = lmbuf[0][q][0], l0 = lmbuf[0][q][1];
        const float m1 = lmbuf[1][q][0], l1 = lmbuf[1][q][1];
        const float m2 = lmbuf[2][q][0], l2 = lmbuf[2][q][1];
        const float m3 = lmbuf[3][q][0], l3 = lmbuf[3][q][1];
        const float M = fmaxf(fmaxf(m0, m1), fmaxf(m2, m3));
        float w0 = l0 * exp2f(m0 - M);
        float w1 = l1 * exp2f(m1 - M);
        float w2 = l2 * exp2f(m2 - M);
        float w3 = l3 * exp2f(m3 - M);
        const float inv = 1.0f / (w0 + w1 + w2 + w3);
        w0 *= inv; w1 *= inv; w2 *= inv; w3 *= inv;

        const ushort8 A0 = *(const ushort8*)(Opart + (0 * 64 + q) * 128 + dseg);
        const ushort8 A1 = *(const ushort8*)(Opart + (1 * 64 + q) * 128 + dseg);
        const ushort8 A2 = *(const ushort8*)(Opart + (2 * 64 + q) * 128 + dseg);
        const ushort8 A3 = *(const ushort8*)(Opart + (3 * 64 + q) * 128 + dseg);
        const ushort8 B0 = *(const ushort8*)(Opart + (0 * 64 + q) * 128 + dseg + 8);
        const ushort8 B1 = *(const ushort8*)(Opart + (1 * 64 + q) * 128 + dseg + 8);
        const ushort8 B2 = *(const ushort8*)(Opart + (2 * 64 + q) * 128 + dseg + 8);
        const ushort8 B3 = *(const ushort8*)(Opart + (3 * 64 + q) * 128 + dseg + 8);

        ushort8 o0, o1;
#pragma unroll
        for (int i = 0; i < 8; ++i) {
            float va = w0 * h2f(A0[i]) + w1 * h2f(A1[i])
                     + w2 * h2f(A2[i]) + w3 * h2f(A3[i]);
            float vb = w0 * h2f(B0[i]) + w1 * h2f(B1[i])
                     + w2 * h2f(B2[i]) + w3 * h2f(B3[i]);
            o0[i] = f2h(fmaxf(va, 0.f));    // relu
            o1[i] = f2h(fmaxf(vb, 0.f));
        }
        *(ushort8*)(olds + q * 136 + dseg)     = o0;
        *(ushort8*)(olds + q * 136 + dseg + 8) = o1;
    }
    __syncthreads();

    // ---- fused output projection: out[b][256][q0..q0+64) ------------------
    {
        const int lr16 = lane & 15;
        const int lg16 = lane >> 4;
        const int ob   = ws * 32;

        f32x4 pacc[2][4];
#pragma unroll
        for (int i = 0; i < 2; ++i)
#pragma unroll
            for (int j = 0; j < 4; ++j) pacc[i][j] = (f32x4){0.f, 0.f, 0.f, 0.f};

        for (int ks = 0; ks < 4; ++ks) {
            ushort8 a0 = *(const ushort8*)
                (wpf + (size_t)(ob + lr16) * DHV + ks * 32 + lg16 * 8);
            ushort8 a1 = *(const ushort8*)
                (wpf + (size_t)(ob + 16 + lr16) * DHV + ks * 32 + lg16 * 8);
#pragma unroll
            for (int qt = 0; qt < 4; ++qt) {
                ushort8 bfr = *(const ushort8*)
                    (olds + (qt * 16 + lr16) * 136 + ks * 32 + lg16 * 8);
                pacc[0][qt] = mfma16(a0, bfr, pacc[0][qt]);
                pacc[1][qt] = mfma16(a1, bfr, pacc[1][qt]);
            }
        }

#pragma unroll
        for (int t2 = 0; t2 < 2; ++t2)
#pragma unroll
            for (int qt = 0; qt < 4; ++qt)
#pragma unroll
                for (int r = 0; r < 4; ++r) {
                    int o = ob + t2 * 16 + lg16 * 4 + r;
                    out[((size_t)b * CIN + o) * N_SP + q0 + qt * 16 + lr16]
                        = pacc[t2][qt][r] + shiftp[o];
                }
    }
}

// ---------------------------------------------------------------------------
extern "C" void kernel_launch(void* const* d_in, const int* in_sizes, int n_in,
                              void* d_out, int out_size, void* d_ws, size_t ws_size,
                              hipStream_t stream)
{
    const float* x    = (const float*)d_in[0];
    const float* w_qk = (const float*)d_in[2];
    const float* g_qk = (const float*)d_in[3];
    const float* b_qk = (const float*)d_in[4];
    const float* m_qk = (const float*)d_in[5];
    const float* v_qk = (const float*)d_in[6];
    const float* w_v  = (const float*)d_in[7];
    const float* g_v  = (const float*)d_in[8];
    const float* b_v  = (const float*)d_in[9];
    const float* m_v  = (const float*)d_in[10];
    const float* v_v  = (const float*)d_in[11];
    const float* w_p  = (const float*)d_in[12];
    const float* g_p  = (const float*)d_in[13];
    const float* b_p  = (const float*)d_in[14];
    const float* m_p  = (const float*)d_in[15];
    const float* v_p  = (const float*)d_in[16];

    char* ws = (char*)d_ws;
    unsigned short* qkT = (unsigned short*)(ws);                    // 512 KB
    unsigned short* Vt  = (unsigned short*)(ws + (1u << 20));       // 4 MB
    unsigned short* wf1 = (unsigned short*)(ws + (9u << 20));       // 72 KB
    float* shift1       = (float*)(ws + (9u << 20) + 80 * 1024);    // 576 B
    unsigned short* wpf = (unsigned short*)(ws + (9u << 20) + 84 * 1024); // 64 KB
    float* shiftp       = (float*)(ws + (9u << 20) + 148 * 1024);   // 1 KB

    fold_weights<<<400, 256, 0, stream>>>(
        w_qk, g_qk, b_qk, m_qk, v_qk,
        w_v, g_v, b_v, m_v, v_v,
        w_p, g_p, b_p, m_p, v_p,
        wf1, shift1, wpf, shiftp);

    proj_qkv<<<dim3(64, 4), 512, 0, stream>>>(x, wf1, shift1, qkT, Vt);

    attn_kernel<<<dim3(64, 4), 512, 0, stream>>>(
        qkT, Vt, wpf, shiftp, (float*)d_out);
}

// Round 18
// 69.480 us; speedup vs baseline: 1.1049x; 1.0070x over previous
//
#include <hip/hip_runtime.h>
#include <cstdint>
#include <cstddef>

// ---------------------------------------------------------------------------
// Attention_Param_sharing_Kv_sharing: B=4, C=256, H=W=64 (N=4096), KD=16,
// NH=8, DH=128.  Gram-matrix attention, one shared KV head.
//
// R17 (verified, 70.0us / attn 53.7): R14 config confirmed as local optimum.
// R18 = R17 + ONE isolated change: pk2 via __builtin_amdgcn_cvt_pkrtz
//   (1 instr per f32-pair vs 2 cvt + or + shift).  Also closes the R10/R11
//   post-mortem: if this passes, the raw-asm permlane32_swap was the bug;
//   if it fails (absmax explodes), cvt_pkrtz is convicted -> revert to R17.
//   RTZ on P in [0,1] and on normalized partials: ~2^-11 rel, invisible.
// History: R4 175 -> R8 138 -> R9 101.6 -> R12 79.1 -> R13 72.0 -> R14 69.9.
// Failed: global key-split (R5), 32-key V tiles (R15), 1024-thr proj (R16).
// ---------------------------------------------------------------------------

typedef __attribute__((ext_vector_type(4)))  float f32x4;
typedef __attribute__((ext_vector_type(16))) float f32x16;
typedef __attribute__((ext_vector_type(8)))  _Float16 half8;
typedef __attribute__((ext_vector_type(8)))  unsigned short ushort8;
typedef __attribute__((ext_vector_type(2)))  unsigned u32x2;
typedef __attribute__((ext_vector_type(4)))  unsigned u32x4;

#define N_SP 4096
#define CIN  256
#define KDIM 16
#define DHV  128

__device__ __forceinline__ unsigned short f2h(float f) {
    _Float16 h = (_Float16)f;             // RNE
    return __builtin_bit_cast(unsigned short, h);
}
__device__ __forceinline__ float h2f(unsigned short u) {
    return (float)__builtin_bit_cast(_Float16, u);
}
__device__ __forceinline__ unsigned pk2(float a, float b) {
    auto h = __builtin_amdgcn_cvt_pkrtz(a, b);   // v_cvt_pkrtz_f16_f32
    return __builtin_bit_cast(unsigned, h);
}
__device__ __forceinline__ unsigned shfl32u(unsigned v, int src) {
    return (unsigned)__shfl((int)v, src, 64);
}
__device__ __forceinline__ f32x4 mfma16(ushort8 a, ushort8 b, f32x4 c) {
    return __builtin_amdgcn_mfma_f32_16x16x32_f16(
        __builtin_bit_cast(half8, a), __builtin_bit_cast(half8, b), c, 0, 0, 0);
}
__device__ __forceinline__ f32x16 mfma32(half8 a, half8 b, f32x16 c) {
    return __builtin_amdgcn_mfma_f32_32x32x16_f16(a, b, c, 0, 0, 0);
}

// ---------------------------------------------------------------------------
// Kernel 0: fold BN into weights.  qk rows pre-scaled by sqrt(log2 e) so
// S arrives multiplied by log2(e) (exp2-domain softmax downstream).
// ---------------------------------------------------------------------------
__global__ __launch_bounds__(256) void fold_weights(
    const float* __restrict__ w_qk, const float* __restrict__ g_qk,
    const float* __restrict__ b_qk, const float* __restrict__ m_qk,
    const float* __restrict__ v_qk,
    const float* __restrict__ w_v, const float* __restrict__ g_v,
    const float* __restrict__ b_v, const float* __restrict__ m_v,
    const float* __restrict__ v_v,
    const float* __restrict__ w_p, const float* __restrict__ g_p,
    const float* __restrict__ b_p, const float* __restrict__ m_p,
    const float* __restrict__ v_p,
    unsigned short* __restrict__ wf1, float* __restrict__ shift1,
    unsigned short* __restrict__ wpf, float* __restrict__ shiftp)
{
    const float SQL2E = 1.2011224087864498f;   // sqrt(log2 e)
    int row = blockIdx.x;
    int t   = threadIdx.x;
    if (row < 144) {
        float s, sh; const float* src;
        if (row < KDIM) {
            s  = g_qk[row] * rsqrtf(v_qk[row] + 1e-5f);
            sh = b_qk[row] - m_qk[row] * s;
            s *= SQL2E; sh *= SQL2E;           // exp2-domain pre-scale
            src = w_qk + row * CIN;
        } else {
            int o = row - KDIM;
            s  = g_v[o] * rsqrtf(v_v[o] + 1e-5f);
            sh = b_v[o] - m_v[o] * s;
            src = w_v + o * CIN;
        }
        wf1[row * CIN + t] = f2h(src[t] * s);
        if (t == 0) shift1[row] = sh;
    } else {
        int o = row - 144;
        float s = g_p[o] * rsqrtf(v_p[o] + 1e-5f);
        if (t < DHV) wpf[o * DHV + t] = f2h(w_p[o * DHV + t] * s);
        if (t == 0) shiftp[o] = b_p[o] - m_p[o] * s;
    }
}

// ---------------------------------------------------------------------------
// Kernel 1: projection GEMM (x read once).  512 thr = 8 waves; wave-halves
// split the 9 o-tiles 5/4 (verified R14 configuration).
// ---------------------------------------------------------------------------
__global__ __launch_bounds__(512) void proj_qkv(
    const float* __restrict__ x,
    const unsigned short* __restrict__ wf1, const float* __restrict__ shift1,
    unsigned short* __restrict__ qkT, unsigned short* __restrict__ Vt)
{
    const int b  = blockIdx.y;
    const int n0 = blockIdx.x * 64;
    const int tid  = threadIdx.x;
    const int w    = tid >> 6;
    const int half = w >> 2;           // o-half: 0 -> ot 0..4, 1 -> ot 5..8
    const int wq   = w & 3;            // n-subtile
    const int lane = tid & 63;
    const int lg   = lane >> 4;
    const int lr   = lane & 15;
    const int n    = n0 + wq * 16 + lr;

    const float* xb = x + (size_t)b * CIN * N_SP;

    if (half == 0) {
        f32x4 acc[5];
#pragma unroll
        for (int i = 0; i < 5; ++i) acc[i] = (f32x4){0.f, 0.f, 0.f, 0.f};
        for (int ks = 0; ks < 8; ++ks) {
            const int cbase = ks * 32 + lg * 8;
            ushort8 bx;
#pragma unroll
            for (int j = 0; j < 8; ++j)
                bx[j] = f2h(xb[(size_t)(cbase + j) * N_SP + n]);
#pragma unroll
            for (int i = 0; i < 5; ++i) {
                ushort8 a = *(const ushort8*)(wf1 + (i * 16 + lr) * CIN + cbase);
                acc[i] = mfma16(a, bx, acc[i]);
            }
        }
#pragma unroll
        for (int i = 0; i < 5; ++i)
#pragma unroll
            for (int r = 0; r < 4; ++r) {
                int o = i * 16 + lg * 4 + r;
                float val = acc[i][r] + shift1[o];
                unsigned short hv = f2h(val);
                if (o < KDIM) qkT[((size_t)b * N_SP + n) * 16 + o] = hv;
                else          Vt[((size_t)b * DHV + (o - KDIM)) * N_SP + n] = hv;
            }
    } else {
        f32x4 acc[4];
#pragma unroll
        for (int i = 0; i < 4; ++i) acc[i] = (f32x4){0.f, 0.f, 0.f, 0.f};
        for (int ks = 0; ks < 8; ++ks) {
            const int cbase = ks * 32 + lg * 8;
            ushort8 bx;
#pragma unroll
            for (int j = 0; j < 8; ++j)
                bx[j] = f2h(xb[(size_t)(cbase + j) * N_SP + n]);
#pragma unroll
            for (int i = 0; i < 4; ++i) {
                ushort8 a = *(const ushort8*)(wf1 + ((i + 5) * 16 + lr) * CIN + cbase);
                acc[i] = mfma16(a, bx, acc[i]);
            }
        }
#pragma unroll
        for (int i = 0; i < 4; ++i)
#pragma unroll
            for (int r = 0; r < 4; ++r) {
                int o = (i + 5) * 16 + lg * 4 + r;
                float val = acc[i][r] + shift1[o];
                Vt[((size_t)b * DHV + (o - KDIM)) * N_SP + n] = f2h(val);
            }
    }
}

// ---------------------------------------------------------------------------
// Stage one 64-key V tile (128 d x 64 halves = 16 KB) via global_load_lds,
// 16 x 1KB chunks; wave p of the stream issues chunks [p*8, p*8+8).
// Source pre-swizzled (rule 21): physical 16B slot s of row d holds
// logical slot s ^ (d&7).
// ---------------------------------------------------------------------------
__device__ __forceinline__ void stage_v(
    const unsigned short* __restrict__ vt_b,
    unsigned short* v_l, int k0, int p, int lane)
{
#pragma unroll
    for (int s = 0; s < 8; ++s) {
        const int vi = p * 8 + s;
        const int d  = vi * 8 + (lane >> 3);
        const int c8 = (lane & 7) ^ ((lane >> 3) & 7);
        const unsigned short* src = vt_b + (size_t)d * N_SP + k0 + c8 * 8;
        __builtin_amdgcn_global_load_lds(
            (const __attribute__((address_space(1))) void*)src,
            (__attribute__((address_space(3))) void*)(v_l + vi * 512),
            16, 0, 0);
    }
}

// V A-frag for PV: A[m=d][k]: lane&31 = d-row, k = (lane>>5)*8 + j.
__device__ __forceinline__ half8 ldv(const unsigned short* vl, int nb, int kc,
                                     int la31, int hi)
{
    const int d = nb * 32 + la31;
    const ushort8 v = *(const ushort8*)
        (vl + d * 64 + (((kc * 2 + hi) ^ (d & 7)) << 3));
    return __builtin_bit_cast(half8, v);
}

// K A-frag for S: A[m=key][k]: lane&31 = key-row, k = (lane>>5)*8 + j.
__device__ __forceinline__ half8 ldk(const unsigned short* qk_b, int krow,
                                     int la31, int hi)
{
    return __builtin_bit_cast(half8,
        *(const ushort8*)(qk_b + (size_t)(krow + la31) * 16 + hi * 8));
}

// ---------------------------------------------------------------------------
// Kernel 2: flash attention + fused output projection (verified R14).
// Grid (64, B), 512 thr = 8 waves = 4 streams x 2 waves.  Stream s: keys
// [s*1024,(s+1)*1024), wave p of stream: queries q0+p*32 .. +31.
// ---------------------------------------------------------------------------
__global__ __launch_bounds__(512, 2) void attn_kernel(
    const unsigned short* __restrict__ qkT,   // [b][n][16] f16 (x sqrt(log2e))
    const unsigned short* __restrict__ Vt,    // [b][128][n] f16
    const unsigned short* __restrict__ wpf,   // [256][128] f16
    const float* __restrict__ shiftp,         // [256] f32
    float* __restrict__ out)                  // [b][256][4096] f32
{
    const int b  = blockIdx.y;
    const int q0 = blockIdx.x * 64;
    const int tid  = threadIdx.x;
    const int ws   = tid >> 6;
    const int strm = ws >> 1;          // key-stream 0..3
    const int p    = ws & 1;           // q-half 0..1
    const int lane = tid & 63;
    const int la31 = lane & 31;
    const int hi   = lane >> 5;

    const unsigned short* qk_b = qkT + (size_t)b * N_SP * 16;
    const unsigned short* vt_b = Vt  + (size_t)b * DHV * N_SP;
    const int kbase = strm * (N_SP / 4);
    const int qrow  = q0 + p * 32;

    // Q B-frag (col n = query = lane&31, k = hi*8+j)
    const half8 aq = __builtin_bit_cast(half8,
        *(const ushort8*)(qk_b + (size_t)(qrow + la31) * 16 + hi * 8));

    f32x16 acc0, acc1, acc2, acc3, z16;
#pragma unroll
    for (int i = 0; i < 16; ++i) { z16[i] = 0.f; }
    acc0 = z16; acc1 = z16; acc2 = z16; acc3 = z16;
    float m_r = -__builtin_inff();
    float l_r = 0.f;

    __shared__ __align__(16) unsigned short v_lds[4][2][128 * 64];  // 128 KB
    __shared__ float lmbuf[4][64][2];                               // 2 KB

    stage_v(vt_b, &v_lds[strm][0][0], kbase, p, lane);
    // K register prefetch for tile 0
    half8 kf0n = ldk(qk_b, kbase, la31, hi);
    half8 kf1n = ldk(qk_b, kbase + 32, la31, hi);

    for (int t = 0; t < 16; ++t) {
        const int cur = t & 1;
        __syncthreads();            // buf[cur] + kf*n ready; prior reads done
        if (t < 15)
            stage_v(vt_b, &v_lds[strm][cur ^ 1][0], kbase + (t + 1) * 64,
                    p, lane);
        const half8 kf0 = kf0n;
        const half8 kf1 = kf1n;
        if (t < 15) {               // prefetch K for tile t+1
            kf0n = ldk(qk_b, kbase + (t + 1) * 64, la31, hi);
            kf1n = ldk(qk_b, kbase + (t + 1) * 64 + 32, la31, hi);
        }
        const unsigned short* vl = &v_lds[strm][cur][0];

        // ---- S' = (K Q^T) * log2e (pre-scaled weights) --------------------
        f32x16 s0 = mfma32(kf0, aq, z16);     // keys k0..k0+31
        f32x16 s1 = mfma32(kf1, aq, z16);     // keys k0+32..k0+63

        // ---- in-lane softmax, 2-domain ------------------------------------
        float mpair[8];
#pragma unroll
        for (int i = 0; i < 8; ++i)
            mpair[i] = fmaxf(fmaxf(s0[i], s0[i + 8]), fmaxf(s1[i], s1[i + 8]));
        float mx = fmaxf(fmaxf(fmaxf(mpair[0], mpair[1]), fmaxf(mpair[2], mpair[3])),
                         fmaxf(fmaxf(mpair[4], mpair[5]), fmaxf(mpair[6], mpair[7])));
        mx = fmaxf(mx, __shfl(mx, lane ^ 32));   // other 32 keys on lane^32

        // defer-max: THR = 8*log2e = 11.54 (P <= 2^11.54 = e^8, fp16-safe)
        if (!__all(mx <= m_r + 11.54f)) {
            float mnew = fmaxf(m_r, mx);
            float sc = exp2f(m_r - mnew);         // first tile: exp2(-inf)=0
            l_r *= sc;
#pragma unroll
            for (int i = 0; i < 16; ++i) {
                acc0[i] *= sc; acc1[i] *= sc; acc2[i] *= sc; acc3[i] *= sc;
            }
            m_r = mnew;
        }
#pragma unroll
        for (int i = 0; i < 16; ++i) s0[i] = exp2f(s0[i] - m_r);
#pragma unroll
        for (int i = 0; i < 16; ++i) s1[i] = exp2f(s1[i] - m_r);
        float rpair[8];
#pragma unroll
        for (int i = 0; i < 8; ++i)
            rpair[i] = (s0[i] + s0[i + 8]) + (s1[i] + s1[i + 8]);
        l_r += ((rpair[0] + rpair[1]) + (rpair[2] + rpair[3]))
             + ((rpair[4] + rpair[5]) + (rpair[6] + rpair[7]));

        // ---- O += V^T P : A = V (m=d), B = P (n=query) --------------------
#define PV_CHUNK(SV, B0, KC)                                               \
        {                                                                  \
            unsigned a0 = pk2(SV[B0 + 0], SV[B0 + 1]);                     \
            unsigned a1 = pk2(SV[B0 + 2], SV[B0 + 3]);                     \
            unsigned a2 = pk2(SV[B0 + 4], SV[B0 + 5]);                     \
            unsigned a3 = pk2(SV[B0 + 6], SV[B0 + 7]);                     \
            unsigned p0 = shfl32u(a0, lane ^ 32);                          \
            unsigned p1 = shfl32u(a1, lane ^ 32);                          \
            unsigned p2 = shfl32u(a2, lane ^ 32);                          \
            unsigned p3 = shfl32u(a3, lane ^ 32);                          \
            u32x4 pw;                                                      \
            pw.x = hi ? p2 : a0;                                           \
            pw.y = hi ? p3 : a1;                                           \
            pw.z = hi ? a2 : p0;                                           \
            pw.w = hi ? a3 : p1;                                           \
            half8 pb = __builtin_bit_cast(half8, pw);                      \
            acc0 = mfma32(ldv(vl, 0, KC, la31, hi), pb, acc0);             \
            acc1 = mfma32(ldv(vl, 1, KC, la31, hi), pb, acc1);             \
            acc2 = mfma32(ldv(vl, 2, KC, la31, hi), pb, acc2);             \
            acc3 = mfma32(ldv(vl, 3, KC, la31, hi), pb, acc3);             \
        }
        PV_CHUNK(s0, 0, 0)
        PV_CHUNK(s0, 8, 1)
        PV_CHUNK(s1, 0, 2)
        PV_CHUNK(s1, 8, 3)
#undef PV_CHUNK
    }

    // ---- finish l: other half of the keys lives on lane^32 ---------------
    l_r = l_r + __shfl(l_r, lane ^ 32);

    __syncthreads();   // all streams done reading V bufs -> safe to reuse

    // ---- publish normalized partial O (fp16) + (m,l) ---------------------
    unsigned short* Opart = &v_lds[0][0][0];  // [4 streams][64 q][128 d] f16
    const int qib = p * 32 + la31;
    if (hi == 0) {
        lmbuf[strm][qib][0] = m_r;
        lmbuf[strm][qib][1] = l_r;
    }
    {
        const float invl = 1.0f / l_r;
        const size_t qoff = ((size_t)strm * 64 + qib) * 128;
#define PUB(ACC, NB)                                                       \
        {                                                                  \
            _Pragma("unroll")                                              \
            for (int rq = 0; rq < 4; ++rq) {                               \
                float v0 = ACC[rq * 4 + 0] * invl;                         \
                float v1 = ACC[rq * 4 + 1] * invl;                         \
                float v2 = ACC[rq * 4 + 2] * invl;                         \
                float v3 = ACC[rq * 4 + 3] * invl;                         \
                u32x2 wv; wv.x = pk2(v0, v1); wv.y = pk2(v2, v3);          \
                *(u32x2*)(Opart + qoff + NB * 32 + rq * 8 + 4 * hi) = wv;  \
            }                                                              \
        }
        PUB(acc0, 0) PUB(acc1, 1) PUB(acc2, 2) PUB(acc3, 3)
#undef PUB
    }
    __syncthreads();

    // ---- merge 4 streams -> olds[64][136] f16 (272B stride: 2-way banks) --
    unsigned short* olds = &v_lds[2][0][0];   // 17.4 KB, dead V region
    {
        const int q    = tid >> 3;
        const int dseg = (tid & 7) * 16;
        const float m0 = lmbuf[0][q][0], l0 = lmbuf[0][q][1];
        const float m1 = lmbuf[1][q][0], l1 = lmbuf[1][q][1];
        const float m2 = lmbuf[2][q][0], l2 = lmbuf[2][q][1];
        const float m3 = lmbuf[3][q][0], l3 = lmbuf[3][q][1];
        const float M = fmaxf(fmaxf(m0, m1), fmaxf(m2, m3));
        float w0 = l0 * exp2f(m0 - M);
        float w1 = l1 * exp2f(m1 - M);
        float w2 = l2 * exp2f(m2 - M);
        float w3 = l3 * exp2f(m3 - M);
        const float inv = 1.0f / (w0 + w1 + w2 + w3);
        w0 *= inv; w1 *= inv; w2 *= inv; w3 *= inv;

        const ushort8 A0 = *(const ushort8*)(Opart + (0 * 64 + q) * 128 + dseg);
        const ushort8 A1 = *(const ushort8*)(Opart + (1 * 64 + q) * 128 + dseg);
        const ushort8 A2 = *(const ushort8*)(Opart + (2 * 64 + q) * 128 + dseg);
        const ushort8 A3 = *(const ushort8*)(Opart + (3 * 64 + q) * 128 + dseg);
        const ushort8 B0 = *(const ushort8*)(Opart + (0 * 64 + q) * 128 + dseg + 8);
        const ushort8 B1 = *(const ushort8*)(Opart + (1 * 64 + q) * 128 + dseg + 8);
        const ushort8 B2 = *(const ushort8*)(Opart + (2 * 64 + q) * 128 + dseg + 8);
        const ushort8 B3 = *(const ushort8*)(Opart + (3 * 64 + q) * 128 + dseg + 8);

        ushort8 o0, o1;
#pragma unroll
        for (int i = 0; i < 8; ++i) {
            float va = w0 * h2f(A0[i]) + w1 * h2f(A1[i])
                     + w2 * h2f(A2[i]) + w3 * h2f(A3[i]);
            float vb = w0 * h2f(B0[i]) + w1 * h2f(B1[i])
                     + w2 * h2f(B2[i]) + w3 * h2f(B3[i]);
            o0[i] = f2h(fmaxf(va, 0.f));    // relu
            o1[i] = f2h(fmaxf(vb, 0.f));
        }
        *(ushort8*)(olds + q * 136 + dseg)     = o0;
        *(ushort8*)(olds + q * 136 + dseg + 8) = o1;
    }
    __syncthreads();

    // ---- fused output projection: out[b][256][q0..q0+64) ------------------
    {
        const int lr16 = lane & 15;
        const int lg16 = lane >> 4;
        const int ob   = ws * 32;

        f32x4 pacc[2][4];
#pragma unroll
        for (int i = 0; i < 2; ++i)
#pragma unroll
            for (int j = 0; j < 4; ++j) pacc[i][j] = (f32x4){0.f, 0.f, 0.f, 0.f};

        for (int ks = 0; ks < 4; ++ks) {
            ushort8 a0 = *(const ushort8*)
                (wpf + (size_t)(ob + lr16) * DHV + ks * 32 + lg16 * 8);
            ushort8 a1 = *(const ushort8*)
                (wpf + (size_t)(ob + 16 + lr16) * DHV + ks * 32 + lg16 * 8);
#pragma unroll
            for (int qt = 0; qt < 4; ++qt) {
                ushort8 bfr = *(const ushort8*)
                    (olds + (qt * 16 + lr16) * 136 + ks * 32 + lg16 * 8);
                pacc[0][qt] = mfma16(a0, bfr, pacc[0][qt]);
                pacc[1][qt] = mfma16(a1, bfr, pacc[1][qt]);
            }
        }

#pragma unroll
        for (int t2 = 0; t2 < 2; ++t2)
#pragma unroll
            for (int qt = 0; qt < 4; ++qt)
#pragma unroll
                for (int r = 0; r < 4; ++r) {
                    int o = ob + t2 * 16 + lg16 * 4 + r;
                    out[((size_t)b * CIN + o) * N_SP + q0 + qt * 16 + lr16]
                        = pacc[t2][qt][r] + shiftp[o];
                }
    }
}

// ---------------------------------------------------------------------------
extern "C" void kernel_launch(void* const* d_in, const int* in_sizes, int n_in,
                              void* d_out, int out_size, void* d_ws, size_t ws_size,
                              hipStream_t stream)
{
    const float* x    = (const float*)d_in[0];
    const float* w_qk = (const float*)d_in[2];
    const float* g_qk = (const float*)d_in[3];
    const float* b_qk = (const float*)d_in[4];
    const float* m_qk = (const float*)d_in[5];
    const float* v_qk = (const float*)d_in[6];
    const float* w_v  = (const float*)d_in[7];
    const float* g_v  = (const float*)d_in[8];
    const float* b_v  = (const float*)d_in[9];
    const float* m_v  = (const float*)d_in[10];
    const float* v_v  = (const float*)d_in[11];
    const float* w_p  = (const float*)d_in[12];
    const float* g_p  = (const float*)d_in[13];
    const float* b_p  = (const float*)d_in[14];
    const float* m_p  = (const float*)d_in[15];
    const float* v_p  = (const float*)d_in[16];

    char* ws = (char*)d_ws;
    unsigned short* qkT = (unsigned short*)(ws);                    // 512 KB
    unsigned short* Vt  = (unsigned short*)(ws + (1u << 20));       // 4 MB
    unsigned short* wf1 = (unsigned short*)(ws + (9u << 20));       // 72 KB
    float* shift1       = (float*)(ws + (9u << 20) + 80 * 1024);    // 576 B
    unsigned short* wpf = (unsigned short*)(ws + (9u << 20) + 84 * 1024); // 64 KB
    float* shiftp       = (float*)(ws + (9u << 20) + 148 * 1024);   // 1 KB

    fold_weights<<<400, 256, 0, stream>>>(
        w_qk, g_qk, b_qk, m_qk, v_qk,
        w_v, g_v, b_v, m_v, v_v,
        w_p, g_p, b_p, m_p, v_p,
        wf1, shift1, wpf, shiftp);

    proj_qkv<<<dim3(64, 4), 512, 0, stream>>>(x, wf1, shift1, qkT, Vt);

    attn_kernel<<<dim3(64, 4), 512, 0, stream>>>(
        qkT, Vt, wpf, shiftp, (float*)d_out);
}

// Round 20
// 69.316 us; speedup vs baseline: 1.1075x; 1.0024x over previous
//
#include <hip/hip_runtime.h>
#include <cstdint>
#include <cstddef>

// ---------------------------------------------------------------------------
// Attention_Param_sharing_Kv_sharing: B=4, C=256, H=W=64 (N=4096), KD=16,
// NH=8, DH=128.  Gram-matrix attention, one shared KV head.
//
// FINAL = verified R18 configuration (69.5us total / attn 53.1us):
//   swapped-32x32x16 flash (in-lane softmax, P in registers), V staged via
//   global_load_lds w/ pre-swizzled source (rule 21), K-reg prefetch,
//   defer-max THR=8*log2e, exp2-domain (weights pre-scaled sqrt(log2 e)),
//   cvt_pkrtz packs, lane^32 exchange via __shfl (VERIFIED), fused output
//   projection in attn epilogue.
// Permlane32_swap post-mortem: BOTH the raw-asm (R11) and builtin (R19)
//   formulations produced fp16-saturated garbage -> my output-mapping model
//   of the instruction is wrong (ISA swaps dst-lo with src-hi, not the
//   both-halves broadcast I assumed).  __shfl exchange stays.
// History: R4 175 -> R8 138 (LDS-shared K/V) -> R9 101.6 (8-wave) ->
//   R12 79.1 (swapped 32x32) -> R13 72.0 -> R14 69.9 (fused) -> R18 69.5.
// Failed: R5 global key-split (L2 flush), R15 32-key tiles (8-way bank
//   conflict), R16 1024-thr proj_qkv, R11/R19 permlane semantics.
// ---------------------------------------------------------------------------

typedef __attribute__((ext_vector_type(4)))  float f32x4;
typedef __attribute__((ext_vector_type(16))) float f32x16;
typedef __attribute__((ext_vector_type(8)))  _Float16 half8;
typedef __attribute__((ext_vector_type(8)))  unsigned short ushort8;
typedef __attribute__((ext_vector_type(2)))  unsigned u32x2;
typedef __attribute__((ext_vector_type(4)))  unsigned u32x4;

#define N_SP 4096
#define CIN  256
#define KDIM 16
#define DHV  128

__device__ __forceinline__ unsigned short f2h(float f) {
    _Float16 h = (_Float16)f;             // RNE
    return __builtin_bit_cast(unsigned short, h);
}
__device__ __forceinline__ float h2f(unsigned short u) {
    return (float)__builtin_bit_cast(_Float16, u);
}
__device__ __forceinline__ unsigned pk2(float a, float b) {
    auto h = __builtin_amdgcn_cvt_pkrtz(a, b);   // v_cvt_pkrtz_f16_f32
    return __builtin_bit_cast(unsigned, h);
}
__device__ __forceinline__ unsigned shfl32u(unsigned v, int src) {
    return (unsigned)__shfl((int)v, src, 64);
}
__device__ __forceinline__ f32x4 mfma16(ushort8 a, ushort8 b, f32x4 c) {
    return __builtin_amdgcn_mfma_f32_16x16x32_f16(
        __builtin_bit_cast(half8, a), __builtin_bit_cast(half8, b), c, 0, 0, 0);
}
__device__ __forceinline__ f32x16 mfma32(half8 a, half8 b, f32x16 c) {
    return __builtin_amdgcn_mfma_f32_32x32x16_f16(a, b, c, 0, 0, 0);
}

// ---------------------------------------------------------------------------
// Kernel 0: fold BN into weights.  qk rows pre-scaled by sqrt(log2 e) so
// S arrives multiplied by log2(e) (exp2-domain softmax downstream).
// ---------------------------------------------------------------------------
__global__ __launch_bounds__(256) void fold_weights(
    const float* __restrict__ w_qk, const float* __restrict__ g_qk,
    const float* __restrict__ b_qk, const float* __restrict__ m_qk,
    const float* __restrict__ v_qk,
    const float* __restrict__ w_v, const float* __restrict__ g_v,
    const float* __restrict__ b_v, const float* __restrict__ m_v,
    const float* __restrict__ v_v,
    const float* __restrict__ w_p, const float* __restrict__ g_p,
    const float* __restrict__ b_p, const float* __restrict__ m_p,
    const float* __restrict__ v_p,
    unsigned short* __restrict__ wf1, float* __restrict__ shift1,
    unsigned short* __restrict__ wpf, float* __restrict__ shiftp)
{
    const float SQL2E = 1.2011224087864498f;   // sqrt(log2 e)
    int row = blockIdx.x;
    int t   = threadIdx.x;
    if (row < 144) {
        float s, sh; const float* src;
        if (row < KDIM) {
            s  = g_qk[row] * rsqrtf(v_qk[row] + 1e-5f);
            sh = b_qk[row] - m_qk[row] * s;
            s *= SQL2E; sh *= SQL2E;           // exp2-domain pre-scale
            src = w_qk + row * CIN;
        } else {
            int o = row - KDIM;
            s  = g_v[o] * rsqrtf(v_v[o] + 1e-5f);
            sh = b_v[o] - m_v[o] * s;
            src = w_v + o * CIN;
        }
        wf1[row * CIN + t] = f2h(src[t] * s);
        if (t == 0) shift1[row] = sh;
    } else {
        int o = row - 144;
        float s = g_p[o] * rsqrtf(v_p[o] + 1e-5f);
        if (t < DHV) wpf[o * DHV + t] = f2h(w_p[o * DHV + t] * s);
        if (t == 0) shiftp[o] = b_p[o] - m_p[o] * s;
    }
}

// ---------------------------------------------------------------------------
// Kernel 1: projection GEMM (x read once).  512 thr = 8 waves; wave-halves
// split the 9 o-tiles 5/4 (verified R14 configuration).
// ---------------------------------------------------------------------------
__global__ __launch_bounds__(512) void proj_qkv(
    const float* __restrict__ x,
    const unsigned short* __restrict__ wf1, const float* __restrict__ shift1,
    unsigned short* __restrict__ qkT, unsigned short* __restrict__ Vt)
{
    const int b  = blockIdx.y;
    const int n0 = blockIdx.x * 64;
    const int tid  = threadIdx.x;
    const int w    = tid >> 6;
    const int half = w >> 2;           // o-half: 0 -> ot 0..4, 1 -> ot 5..8
    const int wq   = w & 3;            // n-subtile
    const int lane = tid & 63;
    const int lg   = lane >> 4;
    const int lr   = lane & 15;
    const int n    = n0 + wq * 16 + lr;

    const float* xb = x + (size_t)b * CIN * N_SP;

    if (half == 0) {
        f32x4 acc[5];
#pragma unroll
        for (int i = 0; i < 5; ++i) acc[i] = (f32x4){0.f, 0.f, 0.f, 0.f};
        for (int ks = 0; ks < 8; ++ks) {
            const int cbase = ks * 32 + lg * 8;
            ushort8 bx;
#pragma unroll
            for (int j = 0; j < 8; ++j)
                bx[j] = f2h(xb[(size_t)(cbase + j) * N_SP + n]);
#pragma unroll
            for (int i = 0; i < 5; ++i) {
                ushort8 a = *(const ushort8*)(wf1 + (i * 16 + lr) * CIN + cbase);
                acc[i] = mfma16(a, bx, acc[i]);
            }
        }
#pragma unroll
        for (int i = 0; i < 5; ++i)
#pragma unroll
            for (int r = 0; r < 4; ++r) {
                int o = i * 16 + lg * 4 + r;
                float val = acc[i][r] + shift1[o];
                unsigned short hv = f2h(val);
                if (o < KDIM) qkT[((size_t)b * N_SP + n) * 16 + o] = hv;
                else          Vt[((size_t)b * DHV + (o - KDIM)) * N_SP + n] = hv;
            }
    } else {
        f32x4 acc[4];
#pragma unroll
        for (int i = 0; i < 4; ++i) acc[i] = (f32x4){0.f, 0.f, 0.f, 0.f};
        for (int ks = 0; ks < 8; ++ks) {
            const int cbase = ks * 32 + lg * 8;
            ushort8 bx;
#pragma unroll
            for (int j = 0; j < 8; ++j)
                bx[j] = f2h(xb[(size_t)(cbase + j) * N_SP + n]);
#pragma unroll
            for (int i = 0; i < 4; ++i) {
                ushort8 a = *(const ushort8*)(wf1 + ((i + 5) * 16 + lr) * CIN + cbase);
                acc[i] = mfma16(a, bx, acc[i]);
            }
        }
#pragma unroll
        for (int i = 0; i < 4; ++i)
#pragma unroll
            for (int r = 0; r < 4; ++r) {
                int o = (i + 5) * 16 + lg * 4 + r;
                float val = acc[i][r] + shift1[o];
                Vt[((size_t)b * DHV + (o - KDIM)) * N_SP + n] = f2h(val);
            }
    }
}

// ---------------------------------------------------------------------------
// Stage one 64-key V tile (128 d x 64 halves = 16 KB) via global_load_lds,
// 16 x 1KB chunks; wave p of the stream issues chunks [p*8, p*8+8).
// Source pre-swizzled (rule 21): physical 16B slot s of row d holds
// logical slot s ^ (d&7).
// ---------------------------------------------------------------------------
__device__ __forceinline__ void stage_v(
    const unsigned short* __restrict__ vt_b,
    unsigned short* v_l, int k0, int p, int lane)
{
#pragma unroll
    for (int s = 0; s < 8; ++s) {
        const int vi = p * 8 + s;
        const int d  = vi * 8 + (lane >> 3);
        const int c8 = (lane & 7) ^ ((lane >> 3) & 7);
        const unsigned short* src = vt_b + (size_t)d * N_SP + k0 + c8 * 8;
        __builtin_amdgcn_global_load_lds(
            (const __attribute__((address_space(1))) void*)src,
            (__attribute__((address_space(3))) void*)(v_l + vi * 512),
            16, 0, 0);
    }
}

// V A-frag for PV: A[m=d][k]: lane&31 = d-row, k = (lane>>5)*8 + j.
__device__ __forceinline__ half8 ldv(const unsigned short* vl, int nb, int kc,
                                     int la31, int hi)
{
    const int d = nb * 32 + la31;
    const ushort8 v = *(const ushort8*)
        (vl + d * 64 + (((kc * 2 + hi) ^ (d & 7)) << 3));
    return __builtin_bit_cast(half8, v);
}

// K A-frag for S: A[m=key][k]: lane&31 = key-row, k = (lane>>5)*8 + j.
__device__ __forceinline__ half8 ldk(const unsigned short* qk_b, int krow,
                                     int la31, int hi)
{
    return __builtin_bit_cast(half8,
        *(const ushort8*)(qk_b + (size_t)(krow + la31) * 16 + hi * 8));
}

// ---------------------------------------------------------------------------
// Kernel 2: flash attention + fused output projection (verified R18).
// Grid (64, B), 512 thr = 8 waves = 4 streams x 2 waves.  Stream s: keys
// [s*1024,(s+1)*1024), wave p of stream: queries q0+p*32 .. +31.
// ---------------------------------------------------------------------------
__global__ __launch_bounds__(512, 2) void attn_kernel(
    const unsigned short* __restrict__ qkT,   // [b][n][16] f16 (x sqrt(log2e))
    const unsigned short* __restrict__ Vt,    // [b][128][n] f16
    const unsigned short* __restrict__ wpf,   // [256][128] f16
    const float* __restrict__ shiftp,         // [256] f32
    float* __restrict__ out)                  // [b][256][4096] f32
{
    const int b  = blockIdx.y;
    const int q0 = blockIdx.x * 64;
    const int tid  = threadIdx.x;
    const int ws   = tid >> 6;
    const int strm = ws >> 1;          // key-stream 0..3
    const int p    = ws & 1;           // q-half 0..1
    const int lane = tid & 63;
    const int la31 = lane & 31;
    const int hi   = lane >> 5;

    const unsigned short* qk_b = qkT + (size_t)b * N_SP * 16;
    const unsigned short* vt_b = Vt  + (size_t)b * DHV * N_SP;
    const int kbase = strm * (N_SP / 4);
    const int qrow  = q0 + p * 32;

    // Q B-frag (col n = query = lane&31, k = hi*8+j)
    const half8 aq = __builtin_bit_cast(half8,
        *(const ushort8*)(qk_b + (size_t)(qrow + la31) * 16 + hi * 8));

    f32x16 acc0, acc1, acc2, acc3, z16;
#pragma unroll
    for (int i = 0; i < 16; ++i) { z16[i] = 0.f; }
    acc0 = z16; acc1 = z16; acc2 = z16; acc3 = z16;
    float m_r = -__builtin_inff();
    float l_r = 0.f;

    __shared__ __align__(16) unsigned short v_lds[4][2][128 * 64];  // 128 KB
    __shared__ float lmbuf[4][64][2];                               // 2 KB

    stage_v(vt_b, &v_lds[strm][0][0], kbase, p, lane);
    // K register prefetch for tile 0
    half8 kf0n = ldk(qk_b, kbase, la31, hi);
    half8 kf1n = ldk(qk_b, kbase + 32, la31, hi);

    for (int t = 0; t < 16; ++t) {
        const int cur = t & 1;
        __syncthreads();            // buf[cur] + kf*n ready; prior reads done
        if (t < 15)
            stage_v(vt_b, &v_lds[strm][cur ^ 1][0], kbase + (t + 1) * 64,
                    p, lane);
        const half8 kf0 = kf0n;
        const half8 kf1 = kf1n;
        if (t < 15) {               // prefetch K for tile t+1
            kf0n = ldk(qk_b, kbase + (t + 1) * 64, la31, hi);
            kf1n = ldk(qk_b, kbase + (t + 1) * 64 + 32, la31, hi);
        }
        const unsigned short* vl = &v_lds[strm][cur][0];

        // ---- S' = (K Q^T) * log2e (pre-scaled weights) --------------------
        f32x16 s0 = mfma32(kf0, aq, z16);     // keys k0..k0+31
        f32x16 s1 = mfma32(kf1, aq, z16);     // keys k0+32..k0+63

        // ---- in-lane softmax, 2-domain ------------------------------------
        float mpair[8];
#pragma unroll
        for (int i = 0; i < 8; ++i)
            mpair[i] = fmaxf(fmaxf(s0[i], s0[i + 8]), fmaxf(s1[i], s1[i + 8]));
        float mx = fmaxf(fmaxf(fmaxf(mpair[0], mpair[1]), fmaxf(mpair[2], mpair[3])),
                         fmaxf(fmaxf(mpair[4], mpair[5]), fmaxf(mpair[6], mpair[7])));
        mx = fmaxf(mx, __shfl(mx, lane ^ 32));   // other 32 keys on lane^32

        // defer-max: THR = 8*log2e = 11.54 (P <= 2^11.54 = e^8, fp16-safe)
        if (!__all(mx <= m_r + 11.54f)) {
            float mnew = fmaxf(m_r, mx);
            float sc = exp2f(m_r - mnew);         // first tile: exp2(-inf)=0
            l_r *= sc;
#pragma unroll
            for (int i = 0; i < 16; ++i) {
                acc0[i] *= sc; acc1[i] *= sc; acc2[i] *= sc; acc3[i] *= sc;
            }
            m_r = mnew;
        }
#pragma unroll
        for (int i = 0; i < 16; ++i) s0[i] = exp2f(s0[i] - m_r);
#pragma unroll
        for (int i = 0; i < 16; ++i) s1[i] = exp2f(s1[i] - m_r);
        float rpair[8];
#pragma unroll
        for (int i = 0; i < 8; ++i)
            rpair[i] = (s0[i] + s0[i + 8]) + (s1[i] + s1[i + 8]);
        l_r += ((rpair[0] + rpair[1]) + (rpair[2] + rpair[3]))
             + ((rpair[4] + rpair[5]) + (rpair[6] + rpair[7]));

        // ---- O += V^T P : A = V (m=d), B = P (n=query) --------------------
#define PV_CHUNK(SV, B0, KC)                                               \
        {                                                                  \
            unsigned a0 = pk2(SV[B0 + 0], SV[B0 + 1]);                     \
            unsigned a1 = pk2(SV[B0 + 2], SV[B0 + 3]);                     \
            unsigned a2 = pk2(SV[B0 + 4], SV[B0 + 5]);                     \
            unsigned a3 = pk2(SV[B0 + 6], SV[B0 + 7]);                     \
            unsigned p0 = shfl32u(a0, lane ^ 32);                          \
            unsigned p1 = shfl32u(a1, lane ^ 32);                          \
            unsigned p2 = shfl32u(a2, lane ^ 32);                          \
            unsigned p3 = shfl32u(a3, lane ^ 32);                          \
            u32x4 pw;                                                      \
            pw.x = hi ? p2 : a0;                                           \
            pw.y = hi ? p3 : a1;                                           \
            pw.z = hi ? a2 : p0;                                           \
            pw.w = hi ? a3 : p1;                                           \
            half8 pb = __builtin_bit_cast(half8, pw);                      \
            acc0 = mfma32(ldv(vl, 0, KC, la31, hi), pb, acc0);             \
            acc1 = mfma32(ldv(vl, 1, KC, la31, hi), pb, acc1);             \
            acc2 = mfma32(ldv(vl, 2, KC, la31, hi), pb, acc2);             \
            acc3 = mfma32(ldv(vl, 3, KC, la31, hi), pb, acc3);             \
        }
        PV_CHUNK(s0, 0, 0)
        PV_CHUNK(s0, 8, 1)
        PV_CHUNK(s1, 0, 2)
        PV_CHUNK(s1, 8, 3)
#undef PV_CHUNK
    }

    // ---- finish l: other half of the keys lives on lane^32 ---------------
    l_r = l_r + __shfl(l_r, lane ^ 32);

    __syncthreads();   // all streams done reading V bufs -> safe to reuse

    // ---- publish normalized partial O (fp16) + (m,l) ---------------------
    unsigned short* Opart = &v_lds[0][0][0];  // [4 streams][64 q][128 d] f16
    const int qib = p * 32 + la31;
    if (hi == 0) {
        lmbuf[strm][qib][0] = m_r;
        lmbuf[strm][qib][1] = l_r;
    }
    {
        const float invl = 1.0f / l_r;
        const size_t qoff = ((size_t)strm * 64 + qib) * 128;
#define PUB(ACC, NB)                                                       \
        {                                                                  \
            _Pragma("unroll")                                              \
            for (int rq = 0; rq < 4; ++rq) {                               \
                float v0 = ACC[rq * 4 + 0] * invl;                         \
                float v1 = ACC[rq * 4 + 1] * invl;                         \
                float v2 = ACC[rq * 4 + 2] * invl;                         \
                float v3 = ACC[rq * 4 + 3] * invl;                         \
                u32x2 wv; wv.x = pk2(v0, v1); wv.y = pk2(v2, v3);          \
                *(u32x2*)(Opart + qoff + NB * 32 + rq * 8 + 4 * hi) = wv;  \
            }                                                              \
        }
        PUB(acc0, 0) PUB(acc1, 1) PUB(acc2, 2) PUB(acc3, 3)
#undef PUB
    }
    __syncthreads();

    // ---- merge 4 streams -> olds[64][136] f16 (272B stride: 2-way banks) --
    unsigned short* olds = &v_lds[2][0][0];   // 17.4 KB, dead V region
    {
        const int q    = tid >> 3;
        const int dseg = (tid & 7) * 16;
        const float m0 = lmbuf[0][q][0], l0 = lmbuf[0][q][1];
        const float m1 = lmbuf[1][q][0], l1 = lmbuf[1][q][1];
        const float m2 = lmbuf[2][q][0], l2 = lmbuf[2][q][1];
        const float m3 = lmbuf[3][q][0], l3 = lmbuf[3][q][1];
        const float M = fmaxf(fmaxf(m0, m1), fmaxf(m2, m3));
        float w0 = l0 * exp2f(m0 - M);
        float w1 = l1 * exp2f(m1 - M);
        float w2 = l2 * exp2f(m2 - M);
        float w3 = l3 * exp2f(m3 - M);
        const float inv = 1.0f / (w0 + w1 + w2 + w3);
        w0 *= inv; w1 *= inv; w2 *= inv; w3 *= inv;

        const ushort8 A0 = *(const ushort8*)(Opart + (0 * 64 + q) * 128 + dseg);
        const ushort8 A1 = *(const ushort8*)(Opart + (1 * 64 + q) * 128 + dseg);
        const ushort8 A2 = *(const ushort8*)(Opart + (2 * 64 + q) * 128 + dseg);
        const ushort8 A3 = *(const ushort8*)(Opart + (3 * 64 + q) * 128 + dseg);
        const ushort8 B0 = *(const ushort8*)(Opart + (0 * 64 + q) * 128 + dseg + 8);
        const ushort8 B1 = *(const ushort8*)(Opart + (1 * 64 + q) * 128 + dseg + 8);
        const ushort8 B2 = *(const ushort8*)(Opart + (2 * 64 + q) * 128 + dseg + 8);
        const ushort8 B3 = *(const ushort8*)(Opart + (3 * 64 + q) * 128 + dseg + 8);

        ushort8 o0, o1;
#pragma unroll
        for (int i = 0; i < 8; ++i) {
            float va = w0 * h2f(A0[i]) + w1 * h2f(A1[i])
                     + w2 * h2f(A2[i]) + w3 * h2f(A3[i]);
            float vb = w0 * h2f(B0[i]) + w1 * h2f(B1[i])
                     + w2 * h2f(B2[i]) + w3 * h2f(B3[i]);
            o0[i] = f2h(fmaxf(va, 0.f));    // relu
            o1[i] = f2h(fmaxf(vb, 0.f));
        }
        *(ushort8*)(olds + q * 136 + dseg)     = o0;
        *(ushort8*)(olds + q * 136 + dseg + 8) = o1;
    }
    __syncthreads();

    // ---- fused output projection: out[b][256][q0..q0+64) ------------------
    {
        const int lr16 = lane & 15;
        const int lg16 = lane >> 4;
        const int ob   = ws * 32;

        f32x4 pacc[2][4];
#pragma unroll
        for (int i = 0; i < 2; ++i)
#pragma unroll
            for (int j = 0; j < 4; ++j) pacc[i][j] = (f32x4){0.f, 0.f, 0.f, 0.f};

        for (int ks = 0; ks < 4; ++ks) {
            ushort8 a0 = *(const ushort8*)
                (wpf + (size_t)(ob + lr16) * DHV + ks * 32 + lg16 * 8);
            ushort8 a1 = *(const ushort8*)
                (wpf + (size_t)(ob + 16 + lr16) * DHV + ks * 32 + lg16 * 8);
#pragma unroll
            for (int qt = 0; qt < 4; ++qt) {
                ushort8 bfr = *(const ushort8*)
                    (olds + (qt * 16 + lr16) * 136 + ks * 32 + lg16 * 8);
                pacc[0][qt] = mfma16(a0, bfr, pacc[0][qt]);
                pacc[1][qt] = mfma16(a1, bfr, pacc[1][qt]);
            }
        }

#pragma unroll
        for (int t2 = 0; t2 < 2; ++t2)
#pragma unroll
            for (int qt = 0; qt < 4; ++qt)
#pragma unroll
                for (int r = 0; r < 4; ++r) {
                    int o = ob + t2 * 16 + lg16 * 4 + r;
                    out[((size_t)b * CIN + o) * N_SP + q0 + qt * 16 + lr16]
                        = pacc[t2][qt][r] + shiftp[o];
                }
    }
}

// ---------------------------------------------------------------------------
extern "C" void kernel_launch(void* const* d_in, const int* in_sizes, int n_in,
                              void* d_out, int out_size, void* d_ws, size_t ws_size,
                              hipStream_t stream)
{
    const float* x    = (const float*)d_in[0];
    const float* w_qk = (const float*)d_in[2];
    const float* g_qk = (const float*)d_in[3];
    const float* b_qk = (const float*)d_in[4];
    const float* m_qk = (const float*)d_in[5];
    const float* v_qk = (const float*)d_in[6];
    const float* w_v  = (const float*)d_in[7];
    const float* g_v  = (const float*)d_in[8];
    const float* b_v  = (const float*)d_in[9];
    const float* m_v  = (const float*)d_in[10];
    const float* v_v  = (const float*)d_in[11];
    const float* w_p  = (const float*)d_in[12];
    const float* g_p  = (const float*)d_in[13];
    const float* b_p  = (const float*)d_in[14];
    const float* m_p  = (const float*)d_in[15];
    const float* v_p  = (const float*)d_in[16];

    char* ws = (char*)d_ws;
    unsigned short* qkT = (unsigned short*)(ws);                    // 512 KB
    unsigned short* Vt  = (unsigned short*)(ws + (1u << 20));       // 4 MB
    unsigned short* wf1 = (unsigned short*)(ws + (9u << 20));       // 72 KB
    float* shift1       = (float*)(ws + (9u << 20) + 80 * 1024);    // 576 B
    unsigned short* wpf = (unsigned short*)(ws + (9u << 20) + 84 * 1024); // 64 KB
    float* shiftp       = (float*)(ws + (9u << 20) + 148 * 1024);   // 1 KB

    fold_weights<<<400, 256, 0, stream>>>(
        w_qk, g_qk, b_qk, m_qk, v_qk,
        w_v, g_v, b_v, m_v, v_v,
        w_p, g_p, b_p, m_p, v_p,
        wf1, shift1, wpf, shiftp);

    proj_qkv<<<dim3(64, 4), 512, 0, stream>>>(x, wf1, shift1, qkT, Vt);

    attn_kernel<<<dim3(64, 4), 512, 0, stream>>>(
        qkT, Vt, wpf, shiftp, (float*)d_out);
}